// Round 5
// baseline (35643.057 us; speedup 1.0000x reference)
//
#include <hip/hip_runtime.h>
#include <cstddef>
#include <cstdint>

#define NB 32     // batch
#define HD 512    // hidden
#define GD 2048   // 4*hidden
#define BSR 528   // LDS B-stage row stride in u16 (16B-aligned rows, bank-spread)

typedef unsigned short u16;
typedef unsigned int u32;
typedef unsigned long long u64;
typedef __attribute__((ext_vector_type(8))) short bf16x8;
typedef __attribute__((ext_vector_type(8))) unsigned short u16x8;
typedef __attribute__((ext_vector_type(4))) float f32x4;

#define MFMA16(a, b, c) __builtin_amdgcn_mfma_f32_16x16x32_bf16((a), (b), (c), 0, 0, 0)
#define AT_LD(p)   __hip_atomic_load((p), __ATOMIC_RELAXED, __HIP_MEMORY_SCOPE_AGENT)
#define AT_ST(p, v) __hip_atomic_store((p), (v), __ATOMIC_RELAXED, __HIP_MEMORY_SCOPE_AGENT)

__device__ __forceinline__ float sigf(float x)   { return 1.0f / (1.0f + __expf(-x)); }
__device__ __forceinline__ float tanhf_(float x) { return 2.0f / (1.0f + __expf(-2.0f * x)) - 1.0f; }

__device__ __forceinline__ u16 f2bf(float x) {
    unsigned u = __float_as_uint(x);
    return (u16)((u + 0x7fffu + ((u >> 16) & 1u)) >> 16);
}
__device__ __forceinline__ float bf2f(u16 h) {
    return __uint_as_float(((unsigned)h) << 16);
}

__device__ __forceinline__ void split8(const float4 a, const float4 b, u16x8& hi, u16x8& lo) {
    float v[8] = {a.x, a.y, a.z, a.w, b.x, b.y, b.z, b.w};
#pragma unroll
    for (int q = 0; q < 8; ++q) {
        const u16 h = f2bf(v[q]);
        hi[q] = h;
        lo[q] = f2bf(v[q] - bf2f(h));
    }
}

__global__ __launch_bounds__(256) void split_kernel(
    const float* __restrict__ src, u16* __restrict__ hi, u16* __restrict__ lo, int n)
{
    const int i = blockIdx.x * 256 + threadIdx.x;
    if (i < n) {
        const float x = src[i];
        const u16 h = f2bf(x);
        hi[i] = h;
        lo[i] = f2bf(x - bf2f(h));
    }
}

__global__ __launch_bounds__(256) void addv_kernel(
    const float* __restrict__ a, const float* __restrict__ b, float* __restrict__ o, int n)
{
    const int i = blockIdx.x * 256 + threadIdx.x;
    if (i < n) o[i] = a[i] + b[i];
}

// pack fp32 -> u32 (bf16 hi | bf16 lo << 16)
__global__ __launch_bounds__(256) void pack_kernel(
    const float* __restrict__ src, u32* __restrict__ dst, int n)
{
    const int i = blockIdx.x * 256 + threadIdx.x;
    if (i < n) {
        const float x = src[i];
        const u16 h = f2bf(x);
        const u16 l = f2bf(x - bf2f(h));
        dst[i] = (u32)h | ((u32)l << 16);
    }
}

// Split-bf16 MFMA GEMM, C tile 64x64, K=512 (unchanged from round 4).
template<int MODE>
__global__ __launch_bounds__(256) void mfma_gemm(
    const float* __restrict__ A, int T, int t0, int tc_bits,
    const float* __restrict__ W, int N,
    const float* __restrict__ b1, const float* __restrict__ b2x,
    float* __restrict__ out, int t_bits, int u_bits)
{
    __shared__ __align__(16) u16 Ah[64][40], Al[64][40], Bh[64][40], Bl[64][40];
    const int tid = threadIdx.x;
    const int m0 = blockIdx.x << 6, n0 = blockIdx.y << 6;

    const int ar = tid >> 2, aks = (tid & 3) << 3;
    const float* aPtr;
    if (MODE == 0) {
        const int rg = m0 + ar;
        const int b = rg >> tc_bits;
        const int tt = t0 + (rg & ((1 << tc_bits) - 1));
        aPtr = A + (((size_t)b * T + tt) << 9) + aks;
    } else {
        aPtr = A + (((size_t)(m0 + ar)) << 9) + aks;
    }
    const float* bPtr = nullptr;
    int bkk = 0, bns = 0;
    if (MODE == 0) {
        bPtr = W + (((size_t)(n0 + ar)) << 9) + aks;
    } else {
        bkk = tid >> 3; bns = (tid & 7) << 3;
        bPtr = W + (size_t)bkk * N + n0 + bns;
    }

    const int lane = tid & 63, wv = tid >> 6;
    const int fr = lane & 15, ko = (lane >> 4) << 3;
    f32x4 acc[4] = {};

    for (int k0 = 0; k0 < HD; k0 += 32) {
        {
            const float4 a1 = *(const float4*)(aPtr + k0);
            const float4 a2 = *(const float4*)(aPtr + k0 + 4);
            u16x8 vh, vl; split8(a1, a2, vh, vl);
            *(u16x8*)&Ah[ar][aks] = vh;
            *(u16x8*)&Al[ar][aks] = vl;
        }
        if (MODE == 0) {
            const float4 w1 = *(const float4*)(bPtr + k0);
            const float4 w2 = *(const float4*)(bPtr + k0 + 4);
            u16x8 vh, vl; split8(w1, w2, vh, vl);
            *(u16x8*)&Bh[ar][aks] = vh;
            *(u16x8*)&Bl[ar][aks] = vl;
        } else {
            const float4 w1 = *(const float4*)(bPtr + (size_t)k0 * N);
            const float4 w2 = *(const float4*)(bPtr + (size_t)k0 * N + 4);
            u16x8 vh, vl; split8(w1, w2, vh, vl);
#pragma unroll
            for (int q = 0; q < 8; ++q) {
                Bh[bns + q][bkk] = vh[q];
                Bl[bns + q][bkk] = vl[q];
            }
        }
        __syncthreads();
        const bf16x8 ahf = *(const bf16x8*)&Ah[(wv << 4) + fr][ko];
        const bf16x8 alf = *(const bf16x8*)&Al[(wv << 4) + fr][ko];
#pragma unroll
        for (int nt = 0; nt < 4; ++nt) {
            const bf16x8 bhf = *(const bf16x8*)&Bh[(nt << 4) + fr][ko];
            const bf16x8 blf = *(const bf16x8*)&Bl[(nt << 4) + fr][ko];
            acc[nt] = MFMA16(ahf, bhf, acc[nt]);
            acc[nt] = MFMA16(ahf, blf, acc[nt]);
            acc[nt] = MFMA16(alf, bhf, acc[nt]);
        }
        __syncthreads();
    }

    const int mlb = (wv << 4) + ((lane >> 4) << 2);
#pragma unroll
    for (int r = 0; r < 4; ++r) {
        const int mg = m0 + mlb + r;
#pragma unroll
        for (int nt = 0; nt < 4; ++nt) {
            const int n = n0 + (nt << 4) + fr;
            const float v = acc[nt][r];
            if (MODE == 0) {
                out[((size_t)mg << 11) + n] = v + b1[n] + b2x[n];
            } else {
                const int bb = mg >> t_bits, tt = mg & ((1 << t_bits) - 1);
                const int uu = n >> 9, hh = n & 511;
                const size_t di = (((size_t)((((bb << t_bits) + tt) << u_bits) + uu)) << 9) + hh;
                out[di] = v + b1[n] + b2x[di];
            }
        }
    }
}

// ---------------- persistent fused 2-layer scan ----------------
// 64 blocks x 512 threads (8 waves). Blocks 0-31: layer0 (16 hidden each);
// 32-63: layer1. Weights live in VGPRs for the whole launch. h crosses blocks
// as packed u32 (bf16 hi|lo) rings via relaxed AGENT atomics; per-step lockstep
// flag barrier (vmcnt(0) + own-flag release + 64-flag spin). NO fences.
// wave role: mt = wv&1 (row half), sel = wv>>1 (K-slice 128 of 512).

#define STEP_BARRIER(JJ) do { \
    asm volatile("s_waitcnt vmcnt(0)" ::: "memory"); \
    __syncthreads(); \
    if (tid == 0) AT_ST(flags + bid, (u32)((JJ) + 1)); \
    if (tid < 64) { \
        int guard_ = 0; \
        while (AT_LD(flags + tid) < (u32)((JJ) + 1) && ++guard_ < (1 << 22)) {} \
    } \
    __builtin_amdgcn_sched_barrier(0); \
    __syncthreads(); \
} while (0)

#define STAGE_WRITE(VV) do { \
    const int xm_ = (sb & 7) << 3; \
    _Pragma("unroll") \
    for (int i_ = 0; i_ < 16; ++i_) { \
        const int e2_ = (((skb << 5) + (i_ << 1)) ^ xm_); \
        const u32 w0_ = (u32)VV[i_], w1_ = (u32)(VV[i_] >> 32); \
        *(u32*)&Bs_h[sb][e2_] = (w0_ & 0xffffu) | (w1_ << 16); \
        *(u32*)&Bs_l[sb][e2_] = (w0_ >> 16) | (w1_ & 0xffff0000u); \
    } \
} while (0)

#define LOAD_A(Aarr, Wh, Wl) do { \
    _Pragma("unroll") \
    for (int rt = 0; rt < 2; ++rt) { \
        const int r_ = (mt << 5) + (rt << 4) + fr; \
        const size_t grow_ = (((size_t)(r_ >> 4)) << 9) + j0 + (r_ & 15); \
        _Pragma("unroll") \
        for (int ck = 0; ck < 4; ++ck) { \
            const size_t o_ = (grow_ << 9) + (sel << 7) + (ck << 5) + ko8; \
            Aarr[rt][ck][0] = *(const bf16x8*)((Wh) + o_); \
            Aarr[rt][ck][1] = *(const bf16x8*)((Wl) + o_); \
        } \
    } \
} while (0)

#define MFMA_PHASE(Aarr) do { \
    _Pragma("unroll") \
    for (int ck = 0; ck < 4; ++ck) { \
        _Pragma("unroll") \
        for (int nt = 0; nt < 2; ++nt) { \
            const int bb_ = (nt << 4) + fr; \
            const int kx_ = ((sel << 7) + (ck << 5) + ko8) ^ ((bb_ & 7) << 3); \
            const bf16x8 bh_ = *(const bf16x8*)&Bs_h[bb_][kx_]; \
            const bf16x8 bl_ = *(const bf16x8*)&Bs_l[bb_][kx_]; \
            _Pragma("unroll") \
            for (int rt = 0; rt < 2; ++rt) { \
                acc[rt][nt] = MFMA16(Aarr[rt][ck][0], bh_, acc[rt][nt]); \
                acc[rt][nt] = MFMA16(Aarr[rt][ck][0], bl_, acc[rt][nt]); \
                acc[rt][nt] = MFMA16(Aarr[rt][ck][1], bh_, acc[rt][nt]); \
            } \
        } \
    } \
} while (0)

#define WRITE_RED() do { \
    _Pragma("unroll") \
    for (int rt = 0; rt < 2; ++rt) \
        _Pragma("unroll") \
        for (int nt = 0; nt < 2; ++nt) \
            _Pragma("unroll") \
            for (int rg = 0; rg < 4; ++rg) \
                red[sel][(mt << 5) + (rt << 4) + (seg << 2) + rg][(nt << 4) + fr] = acc[rt][nt][rg]; \
} while (0)

__global__ __launch_bounds__(512, 2) void lstm_scan2(
    const float* __restrict__ xg, int Tc,
    const u16* __restrict__ w0h, const u16* __restrict__ w0l,
    const u16* __restrict__ w1ih_h, const u16* __restrict__ w1ih_l,
    const u16* __restrict__ w1hh_h, const u16* __restrict__ w1hh_l,
    const float* __restrict__ bsum1,
    u32* __restrict__ ring0, u32* __restrict__ ring1,
    float* __restrict__ c0ws, float* __restrict__ c1ws,
    float* __restrict__ out1, int T, int t0, int NS,
    u32* __restrict__ flags)
{
    __shared__ u16 Bs_h[32][BSR], Bs_l[32][BSR];
    __shared__ float red[4][64][33];
    const int tid = threadIdx.x;
    const int bid = blockIdx.x;
    const bool is0 = bid < 32;
    const int j0 = (is0 ? bid : bid - 32) << 4;
    const int wv = tid >> 6, lane = tid & 63;
    const int mt = wv & 1, sel = wv >> 1;
    const int fr = lane & 15, seg = lane >> 4;
    const int ko8 = seg << 3;
    const int eb = tid >> 4, ejr = tid & 15;       // epilogue (batch, hidden-local)
    const int hidden = j0 + ejr;
    const int sb = tid & 31, skb = tid >> 5;       // stage (batch, k-block)

    if (is0) {
        // ================= layer 0 =================
        bf16x8 A0[2][4][2];
        LOAD_A(A0, w0h, w0l);
        float c_reg = c0ws[((size_t)eb << 9) + hidden];
        for (int jj = 0; jj < NS; ++jj) {
            if (jj < Tc) {
                const int t = t0 + jj;
                // xg prefetch (independent of barrier-protected data)
                float xgv[4];
#pragma unroll
                for (int g = 0; g < 4; ++g)
                    xgv[g] = xg[(((size_t)eb * Tc + jj) << 11) + (g << 9) + hidden];
                // stage h0@(t-1)
                const u64* ps = (const u64*)(ring0 + (((t - 1) & 1) << 14)) + (sb << 8) + (skb << 4);
                u64 v[16];
#pragma unroll
                for (int i = 0; i < 16; ++i) v[i] = AT_LD((u64*)(ps + i));
                STAGE_WRITE(v);
                __syncthreads();
                f32x4 acc[2][2] = {};
                MFMA_PHASE(A0);
                WRITE_RED();
                __syncthreads();
                float gv[4];
#pragma unroll
                for (int g = 0; g < 4; ++g) {
                    const int r = (g << 4) + ejr;
                    gv[g] = red[0][r][eb] + red[1][r][eb] + red[2][r][eb] + red[3][r][eb] + xgv[g];
                }
                c_reg = sigf(gv[1]) * c_reg + sigf(gv[0]) * tanhf_(gv[2]);
                const float h = sigf(gv[3]) * tanhf_(c_reg);
                const u16 hb = f2bf(h);
                const u16 lb = f2bf(h - bf2f(hb));
                AT_ST(ring0 + ((t & 1) << 14) + (eb << 9) + hidden, (u32)hb | ((u32)lb << 16));
            }
            STEP_BARRIER(jj);
        }
        c0ws[((size_t)eb << 9) + hidden] = c_reg;
    } else {
        // ================= layer 1 =================
        bf16x8 Ai[2][4][2], Ahh[2][4][2];
        LOAD_A(Ai, w1ih_h, w1ih_l);
        LOAD_A(Ahh, w1hh_h, w1hh_l);
        float bs_reg[4];
#pragma unroll
        for (int g = 0; g < 4; ++g) bs_reg[g] = bsum1[(g << 9) + hidden];
        float c_reg = c1ws[((size_t)eb << 9) + hidden];
        for (int jj = 0; jj < NS; ++jj) {
            const int t = t0 + jj - 1;
            if (t >= 0) {
                // stage h0@t (phase-A B operand)
                const u64* psA = (const u64*)(ring0 + ((t & 1) << 14)) + (sb << 8) + (skb << 4);
                u64 vA[16];
#pragma unroll
                for (int i = 0; i < 16; ++i) vA[i] = AT_LD((u64*)(psA + i));
                STAGE_WRITE(vA);
                __syncthreads();
                // issue phase-B loads early (h1@(t-1)), write after phase A
                const u64* psB = (const u64*)(ring1 + (((t - 1) & 1) << 14)) + (sb << 8) + (skb << 4);
                u64 vB[16];
#pragma unroll
                for (int i = 0; i < 16; ++i) vB[i] = AT_LD((u64*)(psB + i));
                f32x4 acc[2][2] = {};
                MFMA_PHASE(Ai);
                __syncthreads();
                STAGE_WRITE(vB);
                __syncthreads();
                MFMA_PHASE(Ahh);
                WRITE_RED();
                __syncthreads();
                float gv[4];
#pragma unroll
                for (int g = 0; g < 4; ++g) {
                    const int r = (g << 4) + ejr;
                    gv[g] = red[0][r][eb] + red[1][r][eb] + red[2][r][eb] + red[3][r][eb] + bs_reg[g];
                }
                c_reg = sigf(gv[1]) * c_reg + sigf(gv[0]) * tanhf_(gv[2]);
                const float h = sigf(gv[3]) * tanhf_(c_reg);
                const u16 hb = f2bf(h);
                const u16 lb = f2bf(h - bf2f(hb));
                AT_ST(ring1 + ((t & 1) << 14) + (eb << 9) + hidden, (u32)hb | ((u32)lb << 16));
                out1[(((size_t)eb * T + t) << 9) + hidden] = h;
            }
            STEP_BARRIER(jj);
        }
        c1ws[((size_t)eb << 9) + hidden] = c_reg;
    }
}

extern "C" void kernel_launch(void* const* d_in, const int* in_sizes, int n_in,
                              void* d_out, int out_size, void* d_ws, size_t ws_size,
                              hipStream_t stream)
{
    const float* x[3]   = {(const float*)d_in[0], (const float*)d_in[1],  (const float*)d_in[2]};
    const float* Wih[3] = {(const float*)d_in[3], (const float*)d_in[9],  (const float*)d_in[15]};
    const float* Whh[3] = {(const float*)d_in[4], (const float*)d_in[10], (const float*)d_in[16]};
    const float* bih[3] = {(const float*)d_in[5], (const float*)d_in[11], (const float*)d_in[17]};
    const float* bhh[3] = {(const float*)d_in[6], (const float*)d_in[12], (const float*)d_in[18]};
    const float* h0[3]  = {(const float*)d_in[7], (const float*)d_in[13], (const float*)d_in[19]};
    const float* c0[3]  = {(const float*)d_in[8], (const float*)d_in[14], (const float*)d_in[20]};
    const float* upW[2] = {(const float*)d_in[21], (const float*)d_in[23]};
    const float* upb[2] = {(const float*)d_in[22], (const float*)d_in[24]};

    float* ws = (float*)d_ws;
    float* bufA  = ws;
    float* bufB  = bufA + (size_t)NB * 256 * HD;
    float* c0ws  = bufB + (size_t)NB * 256 * HD;
    float* c1ws  = c0ws + (size_t)NB * HD;
    float* bsum1 = c1ws + (size_t)NB * HD;
    float* xg    = bsum1 + GD;

    const size_t head_f = 2 * (size_t)NB * 256 * HD + 2 * (size_t)NB * HD + GD;
    // tail: 6 weight arrays (GD*HD u16) + 2 rings (2 slots * NB*HD u32) + flags
    const size_t tail_f = (6 * (size_t)GD * HD) / 2 + 4 * (size_t)NB * HD + 256;
    int Tc_cap = 256;
    while (Tc_cap > 32 && (head_f + (size_t)NB * Tc_cap * GD + tail_f) * 4 > ws_size)
        Tc_cap >>= 1;

    u16* w0h    = (u16*)(xg + (size_t)NB * Tc_cap * GD);
    u16* w0l    = w0h + (size_t)GD * HD;
    u16* w1ih_h = w0l + (size_t)GD * HD;
    u16* w1ih_l = w1ih_h + (size_t)GD * HD;
    u16* w1hh_h = w1ih_l + (size_t)GD * HD;
    u16* w1hh_l = w1hh_h + (size_t)GD * HD;
    u32* ring0  = (u32*)(w1hh_l + (size_t)GD * HD);  // 2 slots x 16384 u32
    u32* ring1  = ring0 + 2 * (size_t)NB * HD;
    u32* flags  = ring1 + 2 * (size_t)NB * HD;       // 64 u32

    auto tier = [&](const float* in, float* out1, int T, int tr) {
        const float* Wih0L = Wih[tr];
        const float* Whh0L = Whh[tr];
        const float* Wih1L = Wih[tr] + (size_t)GD * HD;
        const float* Whh1L = Whh[tr] + (size_t)GD * HD;

        split_kernel<<<(GD * HD) / 256, 256, 0, stream>>>(Whh0L, w0h, w0l, GD * HD);
        split_kernel<<<(GD * HD) / 256, 256, 0, stream>>>(Wih1L, w1ih_h, w1ih_l, GD * HD);
        split_kernel<<<(GD * HD) / 256, 256, 0, stream>>>(Whh1L, w1hh_h, w1hh_l, GD * HD);
        addv_kernel<<<GD / 256, 256, 0, stream>>>(bih[tr] + GD, bhh[tr] + GD, bsum1, GD);
        // h0 -> ring slot 1 (t=0 reads slot (t-1)&1 == 1)
        pack_kernel<<<(NB * HD) / 256, 256, 0, stream>>>(h0[tr], ring0 + (1 << 14), NB * HD);
        pack_kernel<<<(NB * HD) / 256, 256, 0, stream>>>(h0[tr] + (size_t)NB * HD, ring1 + (1 << 14), NB * HD);
        hipMemcpyAsync(c0ws, c0[tr], (size_t)NB * HD * sizeof(float),
                       hipMemcpyDeviceToDevice, stream);
        hipMemcpyAsync(c1ws, c0[tr] + (size_t)NB * HD, (size_t)NB * HD * sizeof(float),
                       hipMemcpyDeviceToDevice, stream);

        const int Tc = T < Tc_cap ? T : Tc_cap;
        int tc_bits = 0; while ((1 << tc_bits) < Tc) ++tc_bits;
        for (int t0 = 0; t0 < T; t0 += Tc) {
            dim3 g((NB * Tc) / 64, GD / 64);
            mfma_gemm<0><<<g, 256, 0, stream>>>(in, T, t0, tc_bits, Wih0L, GD,
                                                bih[tr], bhh[tr], xg, 0, 0);
            hipMemsetAsync(flags, 0, 64 * sizeof(u32), stream);
            const bool last = (t0 + Tc >= T);
            const int NS = Tc + (last ? 1 : 0);
            const float* xg_p = xg; int Tc_a = Tc;
            const u16 *a0 = w0h, *a1 = w0l, *a2 = w1ih_h, *a3 = w1ih_l, *a4 = w1hh_h, *a5 = w1hh_l;
            const float* bs_p = bsum1;
            u32 *r0 = ring0, *r1 = ring1;
            float *c0p = c0ws, *c1p = c1ws, *o1 = out1;
            int T_a = T, t0_a = t0, NS_a = NS;
            u32* fl = flags;
            void* args[] = {(void*)&xg_p, (void*)&Tc_a,
                            (void*)&a0, (void*)&a1, (void*)&a2, (void*)&a3, (void*)&a4, (void*)&a5,
                            (void*)&bs_p, (void*)&r0, (void*)&r1,
                            (void*)&c0p, (void*)&c1p, (void*)&o1,
                            (void*)&T_a, (void*)&t0_a, (void*)&NS_a, (void*)&fl};
            hipLaunchCooperativeKernel((const void*)lstm_scan2, dim3(64), dim3(512),
                                       args, 0, stream);
        }
    };

    float* dout = (float*)d_out;

    // Tier 0 (T=128): l1 series -> bufB
    tier(x[0], bufB, 128, 0);
    {   // upsample 0: bufB (B,128,512) -> bufA (B,256,512) + x1
        dim3 g((NB * 128) / 64, 1024 / 64);
        mfma_gemm<1><<<g, 256, 0, stream>>>(bufB, 0, 0, 0, upW[0], 1024,
                                            upb[0], x[1], bufA, 7, 1);
    }
    // Tier 1 (T=256): input bufA, l1 series -> bufB
    tier(bufA, bufB, 256, 1);
    {   // upsample 1: bufB (B,256,512) -> dout (B,2048,512) + x2
        dim3 g((NB * 256) / 64, 4096 / 64);
        mfma_gemm<1><<<g, 256, 0, stream>>>(bufB, 0, 0, 0, upW[1], 4096,
                                            upb[1], x[2], dout, 8, 3);
    }
    // Tier 2 (T=2048): input dout (chunk reads precede in-place l1 writes), l1 -> dout
    tier(dout, dout, 2048, 2);
}

// Round 6
// 28565.753 us; speedup vs baseline: 1.2478x; 1.2478x over previous
//
#include <hip/hip_runtime.h>
#include <cstddef>
#include <cstdint>

#define NB 32     // batch
#define HD 512    // hidden
#define GD 2048   // 4*hidden

typedef unsigned short u16;
typedef unsigned int u32;
typedef unsigned long long u64;
typedef __attribute__((ext_vector_type(8))) short bf16x8;
typedef __attribute__((ext_vector_type(8))) unsigned short u16x8;
typedef __attribute__((ext_vector_type(4))) float f32x4;

#define MFMA16(a, b, c) __builtin_amdgcn_mfma_f32_16x16x32_bf16((a), (b), (c), 0, 0, 0)
#define AT_LD(p)   __hip_atomic_load((p), __ATOMIC_RELAXED, __HIP_MEMORY_SCOPE_AGENT)

// system-coherent 16B load (bypasses stale per-XCD caches), pipelined
#define LDG16(dst, p) \
    asm volatile("global_load_dwordx4 %0, %1, off sc0 sc1" : "=&v"(dst) : "v"(p))
// system-coherent 2B store
#define ST2(p, v) \
    asm volatile("global_store_short %0, %1, off sc0 sc1" :: "v"(p), "v"(v) : "memory")
#define VMCNT0() asm volatile("s_waitcnt vmcnt(0)" ::: "memory")
#define SBAR()   __builtin_amdgcn_sched_barrier(0)

__device__ __forceinline__ float sigf(float x)   { return 1.0f / (1.0f + __expf(-x)); }
__device__ __forceinline__ float tanhf_(float x) { return 2.0f / (1.0f + __expf(-2.0f * x)) - 1.0f; }

__device__ __forceinline__ u16 f2bf(float x) {
    unsigned u = __float_as_uint(x);
    return (u16)((u + 0x7fffu + ((u >> 16) & 1u)) >> 16);
}
__device__ __forceinline__ float bf2f(u16 h) {
    return __uint_as_float(((unsigned)h) << 16);
}

__device__ __forceinline__ void split8(const float4 a, const float4 b, u16x8& hi, u16x8& lo) {
    float v[8] = {a.x, a.y, a.z, a.w, b.x, b.y, b.z, b.w};
#pragma unroll
    for (int q = 0; q < 8; ++q) {
        const u16 h = f2bf(v[q]);
        hi[q] = h;
        lo[q] = f2bf(v[q] - bf2f(h));
    }
}

__global__ __launch_bounds__(256) void split_kernel(
    const float* __restrict__ src, u16* __restrict__ hi, u16* __restrict__ lo, int n)
{
    const int i = blockIdx.x * 256 + threadIdx.x;
    if (i < n) {
        const float x = src[i];
        const u16 h = f2bf(x);
        hi[i] = h;
        lo[i] = f2bf(x - bf2f(h));
    }
}

__global__ __launch_bounds__(256) void addv_kernel(
    const float* __restrict__ a, const float* __restrict__ b, float* __restrict__ o, int n)
{
    const int i = blockIdx.x * 256 + threadIdx.x;
    if (i < n) o[i] = a[i] + b[i];
}

// Split-bf16 MFMA GEMM, C tile 64x64, K=512 (unchanged).
template<int MODE>
__global__ __launch_bounds__(256) void mfma_gemm(
    const float* __restrict__ A, int T, int t0, int tc_bits,
    const float* __restrict__ W, int N,
    const float* __restrict__ b1, const float* __restrict__ b2x,
    float* __restrict__ out, int t_bits, int u_bits)
{
    __shared__ __align__(16) u16 Ah[64][40], Al[64][40], Bh[64][40], Bl[64][40];
    const int tid = threadIdx.x;
    const int m0 = blockIdx.x << 6, n0 = blockIdx.y << 6;

    const int ar = tid >> 2, aks = (tid & 3) << 3;
    const float* aPtr;
    if (MODE == 0) {
        const int rg = m0 + ar;
        const int b = rg >> tc_bits;
        const int tt = t0 + (rg & ((1 << tc_bits) - 1));
        aPtr = A + (((size_t)b * T + tt) << 9) + aks;
    } else {
        aPtr = A + (((size_t)(m0 + ar)) << 9) + aks;
    }
    const float* bPtr = nullptr;
    int bkk = 0, bns = 0;
    if (MODE == 0) {
        bPtr = W + (((size_t)(n0 + ar)) << 9) + aks;
    } else {
        bkk = tid >> 3; bns = (tid & 7) << 3;
        bPtr = W + (size_t)bkk * N + n0 + bns;
    }

    const int lane = tid & 63, wv = tid >> 6;
    const int fr = lane & 15, ko = (lane >> 4) << 3;
    f32x4 acc[4] = {};

    for (int k0 = 0; k0 < HD; k0 += 32) {
        {
            const float4 a1 = *(const float4*)(aPtr + k0);
            const float4 a2 = *(const float4*)(aPtr + k0 + 4);
            u16x8 vh, vl; split8(a1, a2, vh, vl);
            *(u16x8*)&Ah[ar][aks] = vh;
            *(u16x8*)&Al[ar][aks] = vl;
        }
        if (MODE == 0) {
            const float4 w1 = *(const float4*)(bPtr + k0);
            const float4 w2 = *(const float4*)(bPtr + k0 + 4);
            u16x8 vh, vl; split8(w1, w2, vh, vl);
            *(u16x8*)&Bh[ar][aks] = vh;
            *(u16x8*)&Bl[ar][aks] = vl;
        } else {
            const float4 w1 = *(const float4*)(bPtr + (size_t)k0 * N);
            const float4 w2 = *(const float4*)(bPtr + (size_t)k0 * N + 4);
            u16x8 vh, vl; split8(w1, w2, vh, vl);
#pragma unroll
            for (int q = 0; q < 8; ++q) {
                Bh[bns + q][bkk] = vh[q];
                Bl[bns + q][bkk] = vl[q];
            }
        }
        __syncthreads();
        const bf16x8 ahf = *(const bf16x8*)&Ah[(wv << 4) + fr][ko];
        const bf16x8 alf = *(const bf16x8*)&Al[(wv << 4) + fr][ko];
#pragma unroll
        for (int nt = 0; nt < 4; ++nt) {
            const bf16x8 bhf = *(const bf16x8*)&Bh[(nt << 4) + fr][ko];
            const bf16x8 blf = *(const bf16x8*)&Bl[(nt << 4) + fr][ko];
            acc[nt] = MFMA16(ahf, bhf, acc[nt]);
            acc[nt] = MFMA16(ahf, blf, acc[nt]);
            acc[nt] = MFMA16(alf, bhf, acc[nt]);
        }
        __syncthreads();
    }

    const int mlb = (wv << 4) + ((lane >> 4) << 2);
#pragma unroll
    for (int r = 0; r < 4; ++r) {
        const int mg = m0 + mlb + r;
#pragma unroll
        for (int nt = 0; nt < 4; ++nt) {
            const int n = n0 + (nt << 4) + fr;
            const float v = acc[nt][r];
            if (MODE == 0) {
                out[((size_t)mg << 11) + n] = v + b1[n] + b2x[n];
            } else {
                const int bb = mg >> t_bits, tt = mg & ((1 << t_bits) - 1);
                const int uu = n >> 9, hh = n & 511;
                const size_t di = (((size_t)((((bb << t_bits) + tt) << u_bits) + uu)) << 9) + hh;
                out[di] = v + b1[n] + b2x[di];
            }
        }
    }
}

// ---------------- persistent fused 2-layer scan v2 ----------------
// 64 blocks x 512 threads. Blocks 0-31: layer0 (16 hidden units each);
// 32-63: layer1. Weights in VGPRs for the whole launch. h crosses blocks via
// 4-slot split-bf16 rings (ringH/ringL: [slot][batch][512] u16) read/written
// with system-coherent (sc0 sc1) vector ops — no LDS staging, no atomics on
// data. Progress via two monotonic counters (one atomic_add per block/step):
//   l0@jj waits cnt0>=32*jj           (h0@(t-1) ready)  and cnt1>=32*(jj-2)
//         (anti-dep: 4-slot ring gives layer0 two steps of slack)
//   l1@jj waits cnt0>=32*jj (h0@t)    and cnt1>=32*jj   (h1@(t-1))

#define WAIT2(T0, T1) do { \
    if (tid < 2) { \
        const int tgt_ = tid ? (T1) : (T0); \
        u32* cp_ = cnts + (tid << 6); \
        if (tgt_ > 0) { \
            int g_ = 0; \
            while ((int)AT_LD(cp_) < tgt_ && ++g_ < (1 << 24)) {} \
        } \
    } \
    SBAR(); \
    __syncthreads(); \
} while (0)

#define LOAD_A(Aarr, Wh, Wl) do { \
    _Pragma("unroll") \
    for (int rt = 0; rt < 2; ++rt) { \
        const int r_ = (mt << 5) + (rt << 4) + fr; \
        const size_t grow_ = (((size_t)(r_ >> 4)) << 9) + j0 + (r_ & 15); \
        _Pragma("unroll") \
        for (int ck = 0; ck < 4; ++ck) { \
            const size_t o_ = (grow_ << 9) + (sel << 7) + (ck << 5) + ko8; \
            Aarr[rt][ck][0] = *(const bf16x8*)((Wh) + o_); \
            Aarr[rt][ck][1] = *(const bf16x8*)((Wl) + o_); \
        } \
    } \
} while (0)

#define LDG_B(baseH, baseL) do { \
    _Pragma("unroll") \
    for (int ck = 0; ck < 4; ++ck) \
        _Pragma("unroll") \
        for (int nt = 0; nt < 2; ++nt) { \
            const int off_ = (((nt << 4) + fr) << 9) + (sel << 7) + (ck << 5) + ko8; \
            LDG16(bh[ck][nt], (baseH) + off_); \
            LDG16(bl[ck][nt], (baseL) + off_); \
        } \
} while (0)

#define MFMA_PHASE(Aarr) do { \
    _Pragma("unroll") \
    for (int ck = 0; ck < 4; ++ck) \
        _Pragma("unroll") \
        for (int nt = 0; nt < 2; ++nt) \
            _Pragma("unroll") \
            for (int rt = 0; rt < 2; ++rt) { \
                acc[rt][nt] = MFMA16(Aarr[rt][ck][0], bh[ck][nt], acc[rt][nt]); \
                acc[rt][nt] = MFMA16(Aarr[rt][ck][0], bl[ck][nt], acc[rt][nt]); \
                acc[rt][nt] = MFMA16(Aarr[rt][ck][1], bh[ck][nt], acc[rt][nt]); \
            } \
} while (0)

#define WRITE_RED() do { \
    _Pragma("unroll") \
    for (int rt = 0; rt < 2; ++rt) \
        _Pragma("unroll") \
        for (int nt = 0; nt < 2; ++nt) \
            _Pragma("unroll") \
            for (int rg = 0; rg < 4; ++rg) \
                red[sel][(mt << 5) + (rt << 4) + (seg << 2) + rg][(nt << 4) + fr] = acc[rt][nt][rg]; \
} while (0)

__global__ __launch_bounds__(512, 2) void lstm_scan3(
    const float* __restrict__ xg, int Tc,
    const u16* __restrict__ w0h, const u16* __restrict__ w0l,
    const u16* __restrict__ w1ih_h, const u16* __restrict__ w1ih_l,
    const u16* __restrict__ w1hh_h, const u16* __restrict__ w1hh_l,
    const float* __restrict__ bsum1,
    u16* __restrict__ r0H, u16* __restrict__ r0L,
    u16* __restrict__ r1H, u16* __restrict__ r1L,
    float* __restrict__ c0ws, float* __restrict__ c1ws,
    float* __restrict__ out1, int T, int t0, int NS,
    u32* __restrict__ cnts)   // cnts[0]=cnt0 (l0 done), cnts[64]=cnt1 (l1 done)
{
    __shared__ float red[4][64][33];
    const int tid = threadIdx.x;
    const int bid = blockIdx.x;
    const bool is0 = bid < 32;
    const int j0 = (is0 ? bid : bid - 32) << 4;
    const int wv = tid >> 6, lane = tid & 63;
    const int mt = wv & 1, sel = wv >> 1;
    const int fr = lane & 15, seg = lane >> 4;
    const int ko8 = seg << 3;
    const int eb = tid >> 4, ejr = tid & 15;   // epilogue (batch, hidden-local)
    const int hidden = j0 + ejr;

    if (is0) {
        // ================= layer 0 =================
        bf16x8 A0[2][4][2];
        LOAD_A(A0, w0h, w0l);
        float c_reg = c0ws[((size_t)eb << 9) + hidden];
        for (int jj = 0; jj < Tc; ++jj) {
            const int t = t0 + jj;
            // xg prefetch (launch-constant data, plain cached loads)
            float xgv[4];
#pragma unroll
            for (int g = 0; g < 4; ++g)
                xgv[g] = xg[(((size_t)eb * Tc + jj) << 11) + (g << 9) + hidden];
            WAIT2(32 * jj, 32 * (jj - 2));
            // B fragments: h0@(t-1), direct to registers, coherent
            const u16* bH = r0H + ((size_t)((t - 1) & 3) << 14);
            const u16* bL = r0L + ((size_t)((t - 1) & 3) << 14);
            bf16x8 bh[4][2], bl[4][2];
            LDG_B(bH, bL);
            VMCNT0(); SBAR();
            f32x4 acc[2][2] = {};
            MFMA_PHASE(A0);
            WRITE_RED();
            __syncthreads();
            float gv[4];
#pragma unroll
            for (int g = 0; g < 4; ++g) {
                const int r = (g << 4) + ejr;
                gv[g] = red[0][r][eb] + red[1][r][eb] + red[2][r][eb] + red[3][r][eb] + xgv[g];
            }
            __syncthreads();
            c_reg = sigf(gv[1]) * c_reg + sigf(gv[0]) * tanhf_(gv[2]);
            const float h = sigf(gv[3]) * tanhf_(c_reg);
            const u16 hb = f2bf(h);
            const u16 lb = f2bf(h - bf2f(hb));
            const size_t wo = ((size_t)(t & 3) << 14) + (eb << 9) + hidden;
            ST2(r0H + wo, (u32)hb);
            ST2(r0L + wo, (u32)lb);
            VMCNT0();
            __syncthreads();
            if (tid == 0)
                __hip_atomic_fetch_add(cnts, 1u, __ATOMIC_RELAXED, __HIP_MEMORY_SCOPE_AGENT);
        }
        c0ws[((size_t)eb << 9) + hidden] = c_reg;
    } else {
        // ================= layer 1 =================
        bf16x8 Ai[2][4][2], Ahh[2][4][2];
        LOAD_A(Ai, w1ih_h, w1ih_l);
        LOAD_A(Ahh, w1hh_h, w1hh_l);
        float bs_reg[4];
#pragma unroll
        for (int g = 0; g < 4; ++g) bs_reg[g] = bsum1[(g << 9) + hidden];
        float c_reg = c1ws[((size_t)eb << 9) + hidden];
        for (int jj = 0; jj < NS; ++jj) {
            const int t = t0 + jj - 1;
            WAIT2(32 * jj, 32 * jj);
            if (t >= 0) {
                f32x4 acc[2][2] = {};
                bf16x8 bh[4][2], bl[4][2];
                // phase A: Wih1 x h0@t
                {
                    const u16* bH = r0H + ((size_t)(t & 3) << 14);
                    const u16* bL = r0L + ((size_t)(t & 3) << 14);
                    LDG_B(bH, bL);
                    VMCNT0(); SBAR();
                    MFMA_PHASE(Ai);
                }
                // phase B: Whh1 x h1@(t-1)
                {
                    const u16* bH = r1H + ((size_t)((t - 1) & 3) << 14);
                    const u16* bL = r1L + ((size_t)((t - 1) & 3) << 14);
                    LDG_B(bH, bL);
                    VMCNT0(); SBAR();
                    MFMA_PHASE(Ahh);
                }
                WRITE_RED();
                __syncthreads();
                float gv[4];
#pragma unroll
                for (int g = 0; g < 4; ++g) {
                    const int r = (g << 4) + ejr;
                    gv[g] = red[0][r][eb] + red[1][r][eb] + red[2][r][eb] + red[3][r][eb] + bs_reg[g];
                }
                __syncthreads();
                c_reg = sigf(gv[1]) * c_reg + sigf(gv[0]) * tanhf_(gv[2]);
                const float h = sigf(gv[3]) * tanhf_(c_reg);
                const u16 hb = f2bf(h);
                const u16 lb = f2bf(h - bf2f(hb));
                const size_t wo = ((size_t)(t & 3) << 14) + (eb << 9) + hidden;
                ST2(r1H + wo, (u32)hb);
                ST2(r1L + wo, (u32)lb);
                out1[(((size_t)eb * T + t) << 9) + hidden] = h;
                VMCNT0();
            }
            __syncthreads();
            if (tid == 0)
                __hip_atomic_fetch_add(cnts + 64, 1u, __ATOMIC_RELAXED, __HIP_MEMORY_SCOPE_AGENT);
        }
        c1ws[((size_t)eb << 9) + hidden] = c_reg;
    }
}

extern "C" void kernel_launch(void* const* d_in, const int* in_sizes, int n_in,
                              void* d_out, int out_size, void* d_ws, size_t ws_size,
                              hipStream_t stream)
{
    const float* x[3]   = {(const float*)d_in[0], (const float*)d_in[1],  (const float*)d_in[2]};
    const float* Wih[3] = {(const float*)d_in[3], (const float*)d_in[9],  (const float*)d_in[15]};
    const float* Whh[3] = {(const float*)d_in[4], (const float*)d_in[10], (const float*)d_in[16]};
    const float* bih[3] = {(const float*)d_in[5], (const float*)d_in[11], (const float*)d_in[17]};
    const float* bhh[3] = {(const float*)d_in[6], (const float*)d_in[12], (const float*)d_in[18]};
    const float* h0[3]  = {(const float*)d_in[7], (const float*)d_in[13], (const float*)d_in[19]};
    const float* c0[3]  = {(const float*)d_in[8], (const float*)d_in[14], (const float*)d_in[20]};
    const float* upW[2] = {(const float*)d_in[21], (const float*)d_in[23]};
    const float* upb[2] = {(const float*)d_in[22], (const float*)d_in[24]};

    float* ws = (float*)d_ws;
    float* bufA  = ws;
    float* bufB  = bufA + (size_t)NB * 256 * HD;
    float* c0ws  = bufB + (size_t)NB * 256 * HD;
    float* c1ws  = c0ws + (size_t)NB * HD;
    float* bsum1 = c1ws + (size_t)NB * HD;
    float* xg    = bsum1 + GD;

    const size_t head_f = 2 * (size_t)NB * 256 * HD + 2 * (size_t)NB * HD + GD;
    // tail: 6 weight arrays (GD*HD u16) + 4 ring arrays (4 slots * NB*HD u16) + cnts
    const size_t tail_f = 3 * (size_t)GD * HD + 2 * 4 * (size_t)NB * HD + 128;
    int Tc_cap = 256;
    while (Tc_cap > 32 && (head_f + (size_t)NB * Tc_cap * GD + tail_f) * 4 > ws_size)
        Tc_cap >>= 1;

    u16* w0h    = (u16*)(xg + (size_t)NB * Tc_cap * GD);
    u16* w0l    = w0h + (size_t)GD * HD;
    u16* w1ih_h = w0l + (size_t)GD * HD;
    u16* w1ih_l = w1ih_h + (size_t)GD * HD;
    u16* w1hh_h = w1ih_l + (size_t)GD * HD;
    u16* w1hh_l = w1hh_h + (size_t)GD * HD;
    u16* r0H    = w1hh_l + (size_t)GD * HD;   // 4 slots x 16384 u16
    u16* r0L    = r0H + 4 * (size_t)NB * HD;
    u16* r1H    = r0L + 4 * (size_t)NB * HD;
    u16* r1L    = r1H + 4 * (size_t)NB * HD;
    u32* cnts   = (u32*)(r1L + 4 * (size_t)NB * HD);  // cnts[0], cnts[64]

    auto tier = [&](const float* in, float* out1, int T, int tr) {
        const float* Wih0L = Wih[tr];
        const float* Whh0L = Whh[tr];
        const float* Wih1L = Wih[tr] + (size_t)GD * HD;
        const float* Whh1L = Whh[tr] + (size_t)GD * HD;

        split_kernel<<<(GD * HD) / 256, 256, 0, stream>>>(Whh0L, w0h, w0l, GD * HD);
        split_kernel<<<(GD * HD) / 256, 256, 0, stream>>>(Wih1L, w1ih_h, w1ih_l, GD * HD);
        split_kernel<<<(GD * HD) / 256, 256, 0, stream>>>(Whh1L, w1hh_h, w1hh_l, GD * HD);
        addv_kernel<<<GD / 256, 256, 0, stream>>>(bih[tr] + GD, bhh[tr] + GD, bsum1, GD);
        // h0/h1 init -> ring slot 3 (t=0 reads slot (t-1)&3 == 3)
        split_kernel<<<(NB * HD) / 256, 256, 0, stream>>>(
            h0[tr], r0H + 3 * (size_t)NB * HD, r0L + 3 * (size_t)NB * HD, NB * HD);
        split_kernel<<<(NB * HD) / 256, 256, 0, stream>>>(
            h0[tr] + (size_t)NB * HD, r1H + 3 * (size_t)NB * HD, r1L + 3 * (size_t)NB * HD, NB * HD);
        hipMemcpyAsync(c0ws, c0[tr], (size_t)NB * HD * sizeof(float),
                       hipMemcpyDeviceToDevice, stream);
        hipMemcpyAsync(c1ws, c0[tr] + (size_t)NB * HD, (size_t)NB * HD * sizeof(float),
                       hipMemcpyDeviceToDevice, stream);

        const int Tc = T < Tc_cap ? T : Tc_cap;
        int tc_bits = 0; while ((1 << tc_bits) < Tc) ++tc_bits;
        for (int t0 = 0; t0 < T; t0 += Tc) {
            dim3 g((NB * Tc) / 64, GD / 64);
            mfma_gemm<0><<<g, 256, 0, stream>>>(in, T, t0, tc_bits, Wih0L, GD,
                                                bih[tr], bhh[tr], xg, 0, 0);
            hipMemsetAsync(cnts, 0, 128 * sizeof(u32), stream);
            const bool last = (t0 + Tc >= T);
            const int NS = Tc + (last ? 1 : 0);
            const float* xg_p = xg; int Tc_a = Tc;
            const u16 *a0 = w0h, *a1 = w0l, *a2 = w1ih_h, *a3 = w1ih_l, *a4 = w1hh_h, *a5 = w1hh_l;
            const float* bs_p = bsum1;
            u16 *p0H = r0H, *p0L = r0L, *p1H = r1H, *p1L = r1L;
            float *c0p = c0ws, *c1p = c1ws, *o1 = out1;
            int T_a = T, t0_a = t0, NS_a = NS;
            u32* cn = cnts;
            void* args[] = {(void*)&xg_p, (void*)&Tc_a,
                            (void*)&a0, (void*)&a1, (void*)&a2, (void*)&a3, (void*)&a4, (void*)&a5,
                            (void*)&bs_p,
                            (void*)&p0H, (void*)&p0L, (void*)&p1H, (void*)&p1L,
                            (void*)&c0p, (void*)&c1p, (void*)&o1,
                            (void*)&T_a, (void*)&t0_a, (void*)&NS_a, (void*)&cn};
            hipLaunchCooperativeKernel((const void*)lstm_scan3, dim3(64), dim3(512),
                                       args, 0, stream);
        }
    };

    float* dout = (float*)d_out;

    // Tier 0 (T=128): l1 series -> bufB
    tier(x[0], bufB, 128, 0);
    {   // upsample 0: bufB (B,128,512) -> bufA (B,256,512) + x1
        dim3 g((NB * 128) / 64, 1024 / 64);
        mfma_gemm<1><<<g, 256, 0, stream>>>(bufB, 0, 0, 0, upW[0], 1024,
                                            upb[0], x[1], bufA, 7, 1);
    }
    // Tier 1 (T=256): input bufA, l1 series -> bufB
    tier(bufA, bufB, 256, 1);
    {   // upsample 1: bufB (B,256,512) -> dout (B,2048,512) + x2
        dim3 g((NB * 256) / 64, 4096 / 64);
        mfma_gemm<1><<<g, 256, 0, stream>>>(bufB, 0, 0, 0, upW[1], 4096,
                                            upb[1], x[2], dout, 8, 3);
    }
    // Tier 2 (T=2048): input dout (chunk reads precede in-place l1 writes), l1 -> dout
    tier(dout, dout, 2048, 2);
}

// Round 7
// 25051.726 us; speedup vs baseline: 1.4228x; 1.1403x over previous
//
#include <hip/hip_runtime.h>
#include <cstddef>
#include <cstdint>

#define NB 32     // batch
#define HD 512    // hidden
#define GD 2048   // 4*hidden
#define NL0 32    // layer-0 blocks (16 hidden each)
#define NL1 64    // layer-1 blocks (8 hidden each)
#define FSTR 64   // u32 stride between flags (256 B — one L3 line each)

typedef unsigned short u16;
typedef unsigned int u32;
typedef unsigned long long u64;
typedef __attribute__((ext_vector_type(8))) short bf16x8;
typedef __attribute__((ext_vector_type(8))) unsigned short u16x8;
typedef __attribute__((ext_vector_type(4))) float f32x4;

#define MFMA16(a, b, c) __builtin_amdgcn_mfma_f32_16x16x32_bf16((a), (b), (c), 0, 0, 0)
#define AT_LD(p)   __hip_atomic_load((p), __ATOMIC_RELAXED, __HIP_MEMORY_SCOPE_AGENT)

// system-coherent 16B load (bypasses stale per-XCD caches)
#define LDG16(dst, p) \
    asm volatile("global_load_dwordx4 %0, %1, off sc0 sc1" : "=&v"(dst) : "v"(p))
// system-coherent 8B store
#define ST8(p, v) \
    asm volatile("global_store_dwordx2 %0, %1, off sc0 sc1" :: "v"(p), "v"(v) : "memory")
#define VMCNT0() asm volatile("s_waitcnt vmcnt(0)" ::: "memory")
#define SBAR()   __builtin_amdgcn_sched_barrier(0)

__device__ __forceinline__ float sigf(float x)   { return 1.0f / (1.0f + __expf(-x)); }
__device__ __forceinline__ float tanhf_(float x) { return 2.0f / (1.0f + __expf(-2.0f * x)) - 1.0f; }

__device__ __forceinline__ u16 f2bf(float x) {
    unsigned u = __float_as_uint(x);
    return (u16)((u + 0x7fffu + ((u >> 16) & 1u)) >> 16);
}
__device__ __forceinline__ float bf2f(u16 h) {
    return __uint_as_float(((unsigned)h) << 16);
}

__device__ __forceinline__ void split8(const float4 a, const float4 b, u16x8& hi, u16x8& lo) {
    float v[8] = {a.x, a.y, a.z, a.w, b.x, b.y, b.z, b.w};
#pragma unroll
    for (int q = 0; q < 8; ++q) {
        const u16 h = f2bf(v[q]);
        hi[q] = h;
        lo[q] = f2bf(v[q] - bf2f(h));
    }
}

__global__ __launch_bounds__(256) void split_kernel(
    const float* __restrict__ src, u16* __restrict__ hi, u16* __restrict__ lo, int n)
{
    const int i = blockIdx.x * 256 + threadIdx.x;
    if (i < n) {
        const float x = src[i];
        const u16 h = f2bf(x);
        hi[i] = h;
        lo[i] = f2bf(x - bf2f(h));
    }
}

__global__ __launch_bounds__(256) void addv_kernel(
    const float* __restrict__ a, const float* __restrict__ b, float* __restrict__ o, int n)
{
    const int i = blockIdx.x * 256 + threadIdx.x;
    if (i < n) o[i] = a[i] + b[i];
}

// Split-bf16 MFMA GEMM, C tile 64x64, K=512 (unchanged from round 6).
template<int MODE>
__global__ __launch_bounds__(256) void mfma_gemm(
    const float* __restrict__ A, int T, int t0, int tc_bits,
    const float* __restrict__ W, int N,
    const float* __restrict__ b1, const float* __restrict__ b2x,
    float* __restrict__ out, int t_bits, int u_bits)
{
    __shared__ __align__(16) u16 Ah[64][40], Al[64][40], Bh[64][40], Bl[64][40];
    const int tid = threadIdx.x;
    const int m0 = blockIdx.x << 6, n0 = blockIdx.y << 6;

    const int ar = tid >> 2, aks = (tid & 3) << 3;
    const float* aPtr;
    if (MODE == 0) {
        const int rg = m0 + ar;
        const int b = rg >> tc_bits;
        const int tt = t0 + (rg & ((1 << tc_bits) - 1));
        aPtr = A + (((size_t)b * T + tt) << 9) + aks;
    } else {
        aPtr = A + (((size_t)(m0 + ar)) << 9) + aks;
    }
    const float* bPtr = nullptr;
    int bkk = 0, bns = 0;
    if (MODE == 0) {
        bPtr = W + (((size_t)(n0 + ar)) << 9) + aks;
    } else {
        bkk = tid >> 3; bns = (tid & 7) << 3;
        bPtr = W + (size_t)bkk * N + n0 + bns;
    }

    const int lane = tid & 63, wv = tid >> 6;
    const int fr = lane & 15, ko = (lane >> 4) << 3;
    f32x4 acc[4] = {};

    for (int k0 = 0; k0 < HD; k0 += 32) {
        {
            const float4 a1 = *(const float4*)(aPtr + k0);
            const float4 a2 = *(const float4*)(aPtr + k0 + 4);
            u16x8 vh, vl; split8(a1, a2, vh, vl);
            *(u16x8*)&Ah[ar][aks] = vh;
            *(u16x8*)&Al[ar][aks] = vl;
        }
        if (MODE == 0) {
            const float4 w1 = *(const float4*)(bPtr + k0);
            const float4 w2 = *(const float4*)(bPtr + k0 + 4);
            u16x8 vh, vl; split8(w1, w2, vh, vl);
            *(u16x8*)&Bh[ar][aks] = vh;
            *(u16x8*)&Bl[ar][aks] = vl;
        } else {
            const float4 w1 = *(const float4*)(bPtr + (size_t)k0 * N);
            const float4 w2 = *(const float4*)(bPtr + (size_t)k0 * N + 4);
            u16x8 vh, vl; split8(w1, w2, vh, vl);
#pragma unroll
            for (int q = 0; q < 8; ++q) {
                Bh[bns + q][bkk] = vh[q];
                Bl[bns + q][bkk] = vl[q];
            }
        }
        __syncthreads();
        const bf16x8 ahf = *(const bf16x8*)&Ah[(wv << 4) + fr][ko];
        const bf16x8 alf = *(const bf16x8*)&Al[(wv << 4) + fr][ko];
#pragma unroll
        for (int nt = 0; nt < 4; ++nt) {
            const bf16x8 bhf = *(const bf16x8*)&Bh[(nt << 4) + fr][ko];
            const bf16x8 blf = *(const bf16x8*)&Bl[(nt << 4) + fr][ko];
            acc[nt] = MFMA16(ahf, bhf, acc[nt]);
            acc[nt] = MFMA16(ahf, blf, acc[nt]);
            acc[nt] = MFMA16(alf, bhf, acc[nt]);
        }
        __syncthreads();
    }

    const int mlb = (wv << 4) + ((lane >> 4) << 2);
#pragma unroll
    for (int r = 0; r < 4; ++r) {
        const int mg = m0 + mlb + r;
#pragma unroll
        for (int nt = 0; nt < 4; ++nt) {
            const int n = n0 + (nt << 4) + fr;
            const float v = acc[nt][r];
            if (MODE == 0) {
                out[((size_t)mg << 11) + n] = v + b1[n] + b2x[n];
            } else {
                const int bb = mg >> t_bits, tt = mg & ((1 << t_bits) - 1);
                const int uu = n >> 9, hh = n & 511;
                const size_t di = (((size_t)((((bb << t_bits) + tt) << u_bits) + uu)) << 9) + hh;
                out[di] = v + b1[n] + b2x[di];
            }
        }
    }
}

// ---------------- persistent fused 2-layer scan v3 ----------------
// 96 blocks x 512 threads. Blocks [0,32): layer0, 16 hidden units each.
// Blocks [32,96): layer1, 8 hidden units each. Weights VGPR-resident.
// Wave = full K=512, A-rows permuted so reg index == gate: lane (kg,fr) of
// wave (hq,bh) owns (hidden = j0+4*hq+kg, batch = bh*16+fr) — gate combine is
// register-local (no LDS reduction). Per-block padded flags (256B lines),
// one spinner thread per flag.  h rings: 4-slot split-bf16, sc0sc1 ops.
//   l0@jj: flags0>=jj (h0@(t-1)), flags1>=jj-2 (4-slot anti-dep)
//   l1@jj: flags0>=jj (h0@t),     flags1>=jj (h1@(t-1))

#define SPIN_WAIT(TGT0, TGT1) do { \
    if (tid < NL0 + NL1) { \
        const int tgt_ = (tid < NL0) ? (TGT0) : (TGT1); \
        if (tgt_ > 0) { \
            const u32* fp_ = flags + tid * FSTR; \
            int g_ = 0; \
            while ((int)AT_LD(fp_) < tgt_ && ++g_ < (1 << 24)) {} \
        } \
    } \
    SBAR(); \
    __syncthreads(); \
} while (0)

#define B_MFMA_FULLK(BHP, BLP) do { \
    _Pragma("unroll") \
    for (int half = 0; half < 2; ++half) { \
        bf16x8 vb[8], vl[8]; \
        _Pragma("unroll") \
        for (int i = 0; i < 8; ++i) { \
            LDG16(vb[i], (BHP) + (((half << 3) + i) << 5)); \
            LDG16(vl[i], (BLP) + (((half << 3) + i) << 5)); \
        } \
        VMCNT0(); SBAR(); \
        _Pragma("unroll") \
        for (int i = 0; i < 8; ++i) { \
            const int ck_ = (half << 3) + i; \
            s0 = MFMA16(Ah_[ck_], vb[i], s0); \
            s1 = MFMA16(Ah_[ck_], vl[i], s1); \
            s2 = MFMA16(Al_[ck_], vb[i], s2); \
        } \
    } \
} while (0)

#define PACK_PK(P0, P1, P2, P3, HP, LP) \
    const u64 HP = (u64)((P0) & 0xffffu) | ((u64)((P1) & 0xffffu) << 16) \
                 | ((u64)((P2) & 0xffffu) << 32) | ((u64)((P3) & 0xffffu) << 48); \
    const u64 LP = (u64)((P0) >> 16) | ((u64)((P1) >> 16) << 16) \
                 | ((u64)((P2) >> 16) << 32) | ((u64)((P3) >> 16) << 48);

__global__ __launch_bounds__(512, 2) void lstm_scan4(
    const float* __restrict__ xg, int Tc,
    const u16* __restrict__ w0h, const u16* __restrict__ w0l,
    const u16* __restrict__ w1ih_h, const u16* __restrict__ w1ih_l,
    const u16* __restrict__ w1hh_h, const u16* __restrict__ w1hh_l,
    const float* __restrict__ bsum1,
    u16* __restrict__ r0H, u16* __restrict__ r0L,
    u16* __restrict__ r1H, u16* __restrict__ r1L,
    float* __restrict__ c0ws, float* __restrict__ c1ws,
    float* __restrict__ out1, int T, int t0, int NS,
    u32* __restrict__ flags)
{
    __shared__ u32 pk[16][33];
    __shared__ float cmb[4][4][64];
    const int tid = threadIdx.x;
    const int bid = blockIdx.x;
    const int lane = tid & 63, wv = tid >> 6;
    const int fr = lane & 15;          // A-row index / B-col (batch-in-half)
    const int kg = lane >> 4;          // k-subgroup; also epilogue hidden-offset
    const int ko8 = kg << 3;

    if (bid < NL0) {
        // ================= layer 0: 16 hidden / block =================
        const int j0 = bid << 4;
        const int hq = wv >> 1, bh = wv & 1;
        const int jq = j0 + (hq << 2);
        // A-row permutation: gate = fr&3 (-> C reg = gate), hidden off = fr>>2
        const size_t arow = (((size_t)(fr & 3)) << 9) + jq + (fr >> 2);
        bf16x8 Ah_[16], Al_[16];
#pragma unroll
        for (int ck = 0; ck < 16; ++ck) {
            Ah_[ck] = *(const bf16x8*)(w0h + (arow << 9) + (ck << 5) + ko8);
            Al_[ck] = *(const bf16x8*)(w0l + (arow << 9) + (ck << 5) + ko8);
        }
        const int batch = (bh << 4) + fr;
        const int hidden = jq + kg;
        float c_reg = c0ws[((size_t)batch << 9) + hidden];
        const u32 boff = ((u32)batch << 9) + ko8;

        for (int jj = 0; jj < Tc; ++jj) {
            const int t = t0 + jj;
            // xg prefetch (launch-constant, plain cached loads)
            const float* xp = xg + ((((size_t)batch) * Tc + jj) << 11) + hidden;
            const float xv0 = xp[0], xv1 = xp[512], xv2 = xp[1024], xv3 = xp[1536];
            SPIN_WAIT(jj, jj - 2);
            const u16* bHp = r0H + (((size_t)((t - 1) & 3)) << 14) + boff;
            const u16* bLp = r0L + (((size_t)((t - 1) & 3)) << 14) + boff;
            f32x4 s0 = {}, s1 = {}, s2 = {};
            B_MFMA_FULLK(bHp, bLp);
            const float gi = s0[0] + s1[0] + s2[0] + xv0;
            const float gf = s0[1] + s1[1] + s2[1] + xv1;
            const float gg = s0[2] + s1[2] + s2[2] + xv2;
            const float go = s0[3] + s1[3] + s2[3] + xv3;
            c_reg = sigf(gf) * c_reg + sigf(gi) * tanhf_(gg);
            const float h = sigf(go) * tanhf_(c_reg);
            const u16 hb = f2bf(h);
            const u16 lb = f2bf(h - bf2f(hb));
            pk[(hq << 2) + kg][batch] = (u32)hb | ((u32)lb << 16);
            __syncthreads();
            if (tid < 128) {
                const int bt = tid & 31, h4 = (tid >> 5) << 2;
                const u32 p0 = pk[h4 + 0][bt], p1 = pk[h4 + 1][bt];
                const u32 p2 = pk[h4 + 2][bt], p3 = pk[h4 + 3][bt];
                PACK_PK(p0, p1, p2, p3, hp, lp);
                const size_t wo = (((size_t)(t & 3)) << 14) + ((size_t)bt << 9) + j0 + h4;
                ST8(r0H + wo, hp);
                ST8(r0L + wo, lp);
            }
            VMCNT0();
            __syncthreads();
            if (tid == 0)
                __hip_atomic_store(flags + bid * FSTR, (u32)(jj + 1),
                                   __ATOMIC_RELAXED, __HIP_MEMORY_SCOPE_AGENT);
        }
        c0ws[((size_t)batch << 9) + hidden] = c_reg;
    } else {
        // ================= layer 1: 8 hidden / block =================
        const int j0 = (bid - NL0) << 3;
        const int m = wv >> 2, hq = (wv >> 1) & 1, bh = wv & 1;
        const int jq = j0 + (hq << 2);
        const size_t arow = (((size_t)(fr & 3)) << 9) + jq + (fr >> 2);
        const u16* Wh = m ? w1hh_h : w1ih_h;
        const u16* Wl = m ? w1hh_l : w1ih_l;
        bf16x8 Ah_[16], Al_[16];
#pragma unroll
        for (int ck = 0; ck < 16; ++ck) {
            Ah_[ck] = *(const bf16x8*)(Wh + (arow << 9) + (ck << 5) + ko8);
            Al_[ck] = *(const bf16x8*)(Wl + (arow << 9) + (ck << 5) + ko8);
        }
        const int batch = (bh << 4) + fr;
        const int hidden = jq + kg;
        const float bs0 = bsum1[hidden], bs1 = bsum1[512 + hidden];
        const float bs2 = bsum1[1024 + hidden], bs3 = bsum1[1536 + hidden];
        float c_reg = c1ws[((size_t)batch << 9) + hidden];
        const u32 boff = ((u32)batch << 9) + ko8;
        const int pr = (hq << 1) | bh;

        for (int jj = 0; jj < NS; ++jj) {
            const int t = t0 + jj - 1;
            SPIN_WAIT(jj, jj);
            f32x4 s0 = {}, s1 = {}, s2 = {};
            if (t >= 0) {
                const u16 *bHp, *bLp;
                if (m) {
                    bHp = r1H + (((size_t)((t - 1) & 3)) << 14) + boff;
                    bLp = r1L + (((size_t)((t - 1) & 3)) << 14) + boff;
                } else {
                    bHp = r0H + (((size_t)(t & 3)) << 14) + boff;
                    bLp = r0L + (((size_t)(t & 3)) << 14) + boff;
                }
                B_MFMA_FULLK(bHp, bLp);
                if (m == 1) {
#pragma unroll
                    for (int r = 0; r < 4; ++r)
                        cmb[pr][r][lane] = s0[r] + s1[r] + s2[r];
                }
            }
            __syncthreads();
            if (t >= 0 && m == 0) {
                const float gi = s0[0] + s1[0] + s2[0] + cmb[pr][0][lane] + bs0;
                const float gf = s0[1] + s1[1] + s2[1] + cmb[pr][1][lane] + bs1;
                const float gg = s0[2] + s1[2] + s2[2] + cmb[pr][2][lane] + bs2;
                const float go = s0[3] + s1[3] + s2[3] + cmb[pr][3][lane] + bs3;
                c_reg = sigf(gf) * c_reg + sigf(gi) * tanhf_(gg);
                const float h = sigf(go) * tanhf_(c_reg);
                const u16 hb = f2bf(h);
                const u16 lb = f2bf(h - bf2f(hb));
                pk[(hq << 2) + kg][batch] = (u32)hb | ((u32)lb << 16);
            }
            __syncthreads();
            if (t >= 0 && tid < 64) {
                const int bt = tid & 31, h4 = (tid >> 5) << 2;
                const u32 p0 = pk[h4 + 0][bt], p1 = pk[h4 + 1][bt];
                const u32 p2 = pk[h4 + 2][bt], p3 = pk[h4 + 3][bt];
                PACK_PK(p0, p1, p2, p3, hp, lp);
                const size_t wo = (((size_t)(t & 3)) << 14) + ((size_t)bt << 9) + j0 + h4;
                ST8(r1H + wo, hp);
                ST8(r1L + wo, lp);
                float4 o;
                o.x = bf2f((u16)(p0 & 0xffffu)) + bf2f((u16)(p0 >> 16));
                o.y = bf2f((u16)(p1 & 0xffffu)) + bf2f((u16)(p1 >> 16));
                o.z = bf2f((u16)(p2 & 0xffffu)) + bf2f((u16)(p2 >> 16));
                o.w = bf2f((u16)(p3 & 0xffffu)) + bf2f((u16)(p3 >> 16));
                *(float4*)(out1 + (((size_t)bt * T + t) << 9) + j0 + h4) = o;
            }
            VMCNT0();
            __syncthreads();
            if (tid == 0)
                __hip_atomic_store(flags + bid * FSTR, (u32)(jj + 1),
                                   __ATOMIC_RELAXED, __HIP_MEMORY_SCOPE_AGENT);
        }
        if (m == 0) c1ws[((size_t)batch << 9) + hidden] = c_reg;
    }
}

extern "C" void kernel_launch(void* const* d_in, const int* in_sizes, int n_in,
                              void* d_out, int out_size, void* d_ws, size_t ws_size,
                              hipStream_t stream)
{
    const float* x[3]   = {(const float*)d_in[0], (const float*)d_in[1],  (const float*)d_in[2]};
    const float* Wih[3] = {(const float*)d_in[3], (const float*)d_in[9],  (const float*)d_in[15]};
    const float* Whh[3] = {(const float*)d_in[4], (const float*)d_in[10], (const float*)d_in[16]};
    const float* bih[3] = {(const float*)d_in[5], (const float*)d_in[11], (const float*)d_in[17]};
    const float* bhh[3] = {(const float*)d_in[6], (const float*)d_in[12], (const float*)d_in[18]};
    const float* h0[3]  = {(const float*)d_in[7], (const float*)d_in[13], (const float*)d_in[19]};
    const float* c0[3]  = {(const float*)d_in[8], (const float*)d_in[14], (const float*)d_in[20]};
    const float* upW[2] = {(const float*)d_in[21], (const float*)d_in[23]};
    const float* upb[2] = {(const float*)d_in[22], (const float*)d_in[24]};

    float* ws = (float*)d_ws;
    float* bufA  = ws;
    float* bufB  = bufA + (size_t)NB * 256 * HD;
    float* c0ws  = bufB + (size_t)NB * 256 * HD;
    float* c1ws  = c0ws + (size_t)NB * HD;
    float* bsum1 = c1ws + (size_t)NB * HD;
    float* xg    = bsum1 + GD;

    const size_t head_f = 2 * (size_t)NB * 256 * HD + 2 * (size_t)NB * HD + GD;
    // tail: 6 weight arrays (GD*HD u16 = 3M f) + 4 rings (4 slots x NB*HD u16 each
    // = 8*NB*HD f) + flags (96*FSTR u32)
    const size_t tail_f = 3 * (size_t)GD * HD + 8 * (size_t)NB * HD + 96 * FSTR + 64;
    int Tc_cap = 256;
    while (Tc_cap > 32 && (head_f + (size_t)NB * Tc_cap * GD + tail_f) * 4 > ws_size)
        Tc_cap >>= 1;

    u16* w0h    = (u16*)(xg + (size_t)NB * Tc_cap * GD);
    u16* w0l    = w0h + (size_t)GD * HD;
    u16* w1ih_h = w0l + (size_t)GD * HD;
    u16* w1ih_l = w1ih_h + (size_t)GD * HD;
    u16* w1hh_h = w1ih_l + (size_t)GD * HD;
    u16* w1hh_l = w1hh_h + (size_t)GD * HD;
    u16* r0H    = w1hh_l + (size_t)GD * HD;   // 4 slots x 16384 u16
    u16* r0L    = r0H + 4 * (size_t)NB * HD;
    u16* r1H    = r0L + 4 * (size_t)NB * HD;
    u16* r1L    = r1H + 4 * (size_t)NB * HD;
    u32* flags  = (u32*)(r1L + 4 * (size_t)NB * HD);  // 96 flags, 256B apart

    auto tier = [&](const float* in, float* out1, int T, int tr) {
        const float* Wih0L = Wih[tr];
        const float* Whh0L = Whh[tr];
        const float* Wih1L = Wih[tr] + (size_t)GD * HD;
        const float* Whh1L = Whh[tr] + (size_t)GD * HD;

        split_kernel<<<(GD * HD) / 256, 256, 0, stream>>>(Whh0L, w0h, w0l, GD * HD);
        split_kernel<<<(GD * HD) / 256, 256, 0, stream>>>(Wih1L, w1ih_h, w1ih_l, GD * HD);
        split_kernel<<<(GD * HD) / 256, 256, 0, stream>>>(Whh1L, w1hh_h, w1hh_l, GD * HD);
        addv_kernel<<<GD / 256, 256, 0, stream>>>(bih[tr] + GD, bhh[tr] + GD, bsum1, GD);
        // h0/h1 init -> ring slot 3 (t=0 reads slot (t-1)&3 == 3)
        split_kernel<<<(NB * HD) / 256, 256, 0, stream>>>(
            h0[tr], r0H + 3 * (size_t)NB * HD, r0L + 3 * (size_t)NB * HD, NB * HD);
        split_kernel<<<(NB * HD) / 256, 256, 0, stream>>>(
            h0[tr] + (size_t)NB * HD, r1H + 3 * (size_t)NB * HD, r1L + 3 * (size_t)NB * HD, NB * HD);
        hipMemcpyAsync(c0ws, c0[tr], (size_t)NB * HD * sizeof(float),
                       hipMemcpyDeviceToDevice, stream);
        hipMemcpyAsync(c1ws, c0[tr] + (size_t)NB * HD, (size_t)NB * HD * sizeof(float),
                       hipMemcpyDeviceToDevice, stream);

        const int Tc = T < Tc_cap ? T : Tc_cap;
        int tc_bits = 0; while ((1 << tc_bits) < Tc) ++tc_bits;
        for (int t0 = 0; t0 < T; t0 += Tc) {
            dim3 g((NB * Tc) / 64, GD / 64);
            mfma_gemm<0><<<g, 256, 0, stream>>>(in, T, t0, tc_bits, Wih0L, GD,
                                                bih[tr], bhh[tr], xg, 0, 0);
            hipMemsetAsync(flags, 0, 96 * FSTR * sizeof(u32), stream);
            const bool last = (t0 + Tc >= T);
            const int NS = Tc + (last ? 1 : 0);
            const float* xg_p = xg; int Tc_a = Tc;
            const u16 *a0 = w0h, *a1 = w0l, *a2 = w1ih_h, *a3 = w1ih_l, *a4 = w1hh_h, *a5 = w1hh_l;
            const float* bs_p = bsum1;
            u16 *p0H = r0H, *p0L = r0L, *p1H = r1H, *p1L = r1L;
            float *c0p = c0ws, *c1p = c1ws, *o1 = out1;
            int T_a = T, t0_a = t0, NS_a = NS;
            u32* fl = flags;
            void* args[] = {(void*)&xg_p, (void*)&Tc_a,
                            (void*)&a0, (void*)&a1, (void*)&a2, (void*)&a3, (void*)&a4, (void*)&a5,
                            (void*)&bs_p,
                            (void*)&p0H, (void*)&p0L, (void*)&p1H, (void*)&p1L,
                            (void*)&c0p, (void*)&c1p, (void*)&o1,
                            (void*)&T_a, (void*)&t0_a, (void*)&NS_a, (void*)&fl};
            hipLaunchCooperativeKernel((const void*)lstm_scan4, dim3(NL0 + NL1), dim3(512),
                                       args, 0, stream);
        }
    };

    float* dout = (float*)d_out;

    // Tier 0 (T=128): l1 series -> bufB
    tier(x[0], bufB, 128, 0);
    {   // upsample 0: bufB (B,128,512) -> bufA (B,256,512) + x1
        dim3 g((NB * 128) / 64, 1024 / 64);
        mfma_gemm<1><<<g, 256, 0, stream>>>(bufB, 0, 0, 0, upW[0], 1024,
                                            upb[0], x[1], bufA, 7, 1);
    }
    // Tier 1 (T=256): input bufA, l1 series -> bufB
    tier(bufA, bufB, 256, 1);
    {   // upsample 1: bufB (B,256,512) -> dout (B,2048,512) + x2
        dim3 g((NB * 256) / 64, 4096 / 64);
        mfma_gemm<1><<<g, 256, 0, stream>>>(bufB, 0, 0, 0, upW[1], 4096,
                                            upb[1], x[2], dout, 8, 3);
    }
    // Tier 2 (T=2048): input dout (chunk reads precede in-place l1 writes), l1 -> dout
    tier(dout, dout, 2048, 2);
}

// Round 8
// 15937.167 us; speedup vs baseline: 2.2365x; 1.5719x over previous
//
#include <hip/hip_runtime.h>
#include <cstddef>
#include <cstdint>

#define NB 32     // batch
#define HD 512    // hidden
#define GD 2048   // 4*hidden
#define NL0 32    // layer-0 blocks (16 hidden each)
#define NL1 64    // layer-1 blocks (8 hidden each)
#define FSTR 64   // u32 stride between flags (256 B each)
#define NSLOT 8   // ring slots

typedef unsigned short u16;
typedef unsigned int u32;
typedef unsigned long long u64;
typedef __attribute__((ext_vector_type(8))) short bf16x8;
typedef __attribute__((ext_vector_type(8))) unsigned short u16x8;
typedef __attribute__((ext_vector_type(4))) float f32x4;

#define MFMA16(a, b, c) __builtin_amdgcn_mfma_f32_16x16x32_bf16((a), (b), (c), 0, 0, 0)
#define AT_LD(p)   __hip_atomic_load((p), __ATOMIC_RELAXED, __HIP_MEMORY_SCOPE_AGENT)

#define LDG16(dst, p) \
    asm volatile("global_load_dwordx4 %0, %1, off sc0 sc1" : "=&v"(dst) : "v"(p))
#define ST8(p, v) \
    asm volatile("global_store_dwordx2 %0, %1, off sc0 sc1" :: "v"(p), "v"(v) : "memory")
#define VMCNT0() asm volatile("s_waitcnt vmcnt(0)" ::: "memory")
#define SBAR()   __builtin_amdgcn_sched_barrier(0)

__device__ __forceinline__ float sigf(float x)   { return 1.0f / (1.0f + __expf(-x)); }
__device__ __forceinline__ float tanhf_(float x) { return 2.0f / (1.0f + __expf(-2.0f * x)) - 1.0f; }

__device__ __forceinline__ u16 f2bf(float x) {
    unsigned u = __float_as_uint(x);
    return (u16)((u + 0x7fffu + ((u >> 16) & 1u)) >> 16);
}
__device__ __forceinline__ float bf2f(u16 h) {
    return __uint_as_float(((unsigned)h) << 16);
}

__device__ __forceinline__ void split8(const float4 a, const float4 b, u16x8& hi, u16x8& lo) {
    float v[8] = {a.x, a.y, a.z, a.w, b.x, b.y, b.z, b.w};
#pragma unroll
    for (int q = 0; q < 8; ++q) {
        const u16 h = f2bf(v[q]);
        hi[q] = h;
        lo[q] = f2bf(v[q] - bf2f(h));
    }
}

__global__ __launch_bounds__(256) void split_kernel(
    const float* __restrict__ src, u16* __restrict__ hi, u16* __restrict__ lo, int n)
{
    const int i = blockIdx.x * 256 + threadIdx.x;
    if (i < n) {
        const float x = src[i];
        const u16 h = f2bf(x);
        hi[i] = h;
        lo[i] = f2bf(x - bf2f(h));
    }
}

__global__ __launch_bounds__(256) void addv_kernel(
    const float* __restrict__ a, const float* __restrict__ b, float* __restrict__ o, int n)
{
    const int i = blockIdx.x * 256 + threadIdx.x;
    if (i < n) o[i] = a[i] + b[i];
}

// Split-bf16 MFMA GEMM, C tile 64x64, K=512 (unchanged).
template<int MODE>
__global__ __launch_bounds__(256) void mfma_gemm(
    const float* __restrict__ A, int T, int t0, int tc_bits,
    const float* __restrict__ W, int N,
    const float* __restrict__ b1, const float* __restrict__ b2x,
    float* __restrict__ out, int t_bits, int u_bits)
{
    __shared__ __align__(16) u16 Ah[64][40], Al[64][40], Bh[64][40], Bl[64][40];
    const int tid = threadIdx.x;
    const int m0 = blockIdx.x << 6, n0 = blockIdx.y << 6;

    const int ar = tid >> 2, aks = (tid & 3) << 3;
    const float* aPtr;
    if (MODE == 0) {
        const int rg = m0 + ar;
        const int b = rg >> tc_bits;
        const int tt = t0 + (rg & ((1 << tc_bits) - 1));
        aPtr = A + (((size_t)b * T + tt) << 9) + aks;
    } else {
        aPtr = A + (((size_t)(m0 + ar)) << 9) + aks;
    }
    const float* bPtr = nullptr;
    int bkk = 0, bns = 0;
    if (MODE == 0) {
        bPtr = W + (((size_t)(n0 + ar)) << 9) + aks;
    } else {
        bkk = tid >> 3; bns = (tid & 7) << 3;
        bPtr = W + (size_t)bkk * N + n0 + bns;
    }

    const int lane = tid & 63, wv = tid >> 6;
    const int fr = lane & 15, ko = (lane >> 4) << 3;
    f32x4 acc[4] = {};

    for (int k0 = 0; k0 < HD; k0 += 32) {
        {
            const float4 a1 = *(const float4*)(aPtr + k0);
            const float4 a2 = *(const float4*)(aPtr + k0 + 4);
            u16x8 vh, vl; split8(a1, a2, vh, vl);
            *(u16x8*)&Ah[ar][aks] = vh;
            *(u16x8*)&Al[ar][aks] = vl;
        }
        if (MODE == 0) {
            const float4 w1 = *(const float4*)(bPtr + k0);
            const float4 w2 = *(const float4*)(bPtr + k0 + 4);
            u16x8 vh, vl; split8(w1, w2, vh, vl);
            *(u16x8*)&Bh[ar][aks] = vh;
            *(u16x8*)&Bl[ar][aks] = vl;
        } else {
            const float4 w1 = *(const float4*)(bPtr + (size_t)k0 * N);
            const float4 w2 = *(const float4*)(bPtr + (size_t)k0 * N + 4);
            u16x8 vh, vl; split8(w1, w2, vh, vl);
#pragma unroll
            for (int q = 0; q < 8; ++q) {
                Bh[bns + q][bkk] = vh[q];
                Bl[bns + q][bkk] = vl[q];
            }
        }
        __syncthreads();
        const bf16x8 ahf = *(const bf16x8*)&Ah[(wv << 4) + fr][ko];
        const bf16x8 alf = *(const bf16x8*)&Al[(wv << 4) + fr][ko];
#pragma unroll
        for (int nt = 0; nt < 4; ++nt) {
            const bf16x8 bhf = *(const bf16x8*)&Bh[(nt << 4) + fr][ko];
            const bf16x8 blf = *(const bf16x8*)&Bl[(nt << 4) + fr][ko];
            acc[nt] = MFMA16(ahf, bhf, acc[nt]);
            acc[nt] = MFMA16(ahf, blf, acc[nt]);
            acc[nt] = MFMA16(alf, bhf, acc[nt]);
        }
        __syncthreads();
    }

    const int mlb = (wv << 4) + ((lane >> 4) << 2);
#pragma unroll
    for (int r = 0; r < 4; ++r) {
        const int mg = m0 + mlb + r;
#pragma unroll
        for (int nt = 0; nt < 4; ++nt) {
            const int n = n0 + (nt << 4) + fr;
            const float v = acc[nt][r];
            if (MODE == 0) {
                out[((size_t)mg << 11) + n] = v + b1[n] + b2x[n];
            } else {
                const int bb = mg >> t_bits, tt = mg & ((1 << t_bits) - 1);
                const int uu = n >> 9, hh = n & 511;
                const size_t di = (((size_t)((((bb << t_bits) + tt) << u_bits) + uu)) << 9) + hh;
                out[di] = v + b1[n] + b2x[di];
            }
        }
    }
}

// ---------------- persistent fused 2-layer scan v4 ----------------
// 96 blocks x 512 threads. [0,32): layer0 (16 hidden); [32,96): layer1 (8 hidden).
// Waves split K: wave = (kq 0..3, bh 0..1); each B element loaded once/block.
// A-hi in VGPRs (16 frags/wave); A-lo staged once to LDS, ds_read per step.
// Cross-kq combine via padded LDS (stride 20 floats, f32x4). Gate == C-reg.
// Rings 8-slot split-bf16, sc0sc1 ops; per-block padded flags.
//   l0@jj: flags0 >= jj, flags1 >= jj-6   |   l1@jj: flags0 >= jj, flags1 >= jj

#define SPIN_WAIT(TGT0, TGT1) do { \
    if (tid < NL0 + NL1) { \
        const int tgt_ = (tid < NL0) ? (TGT0) : (TGT1); \
        if (tgt_ > 0) { \
            const u32* fp_ = flags + tid * FSTR; \
            int g_ = 0; \
            while ((int)AT_LD(fp_) < tgt_ && ++g_ < (1 << 24)) {} \
        } \
    } \
    SBAR(); \
    __syncthreads(); \
} while (0)

__global__ __launch_bounds__(512, 2) void lstm_scan5(
    const float* __restrict__ xg, int Tc,
    const u16* __restrict__ w0h, const u16* __restrict__ w0l,
    const u16* __restrict__ w1ih_h, const u16* __restrict__ w1ih_l,
    const u16* __restrict__ w1hh_h, const u16* __restrict__ w1hh_l,
    const float* __restrict__ bsum1,
    u16* __restrict__ r0H, u16* __restrict__ r0L,
    u16* __restrict__ r1H, u16* __restrict__ r1L,
    float* __restrict__ c0ws, float* __restrict__ c1ws,
    float* __restrict__ out1, int T, int t0, int NS,
    u32* __restrict__ flags)
{
    __shared__ __align__(16) u16 sA[32768];            // A-lo frags, 64 KB
    __shared__ __align__(16) float sred[16 * 32 * 20]; // 40 KB (l1 uses half)
    __shared__ u32 spk[16][33];
    const int tid = threadIdx.x;
    const int bid = blockIdx.x;
    const int lane = tid & 63, wv = tid >> 6;
    const int kq = wv >> 1, bh = wv & 1;
    const int fr = lane & 15, kg = lane >> 4;
    const int batch = (bh << 4) + fr;
    const int eb = tid & 31;            // epilogue batch
    const u32 bko = ((u32)batch << 9) + (kq << 7) + (kg << 3);  // ring elem offset

    if (bid < NL0) {
        // ================= layer 0: 16 hidden =================
        const int j0 = bid << 4;
        // stage A-lo to LDS: idx -> (hq, f, l)
#pragma unroll
        for (int i = 0; i < 8; ++i) {
            const int idx = tid + (i << 9);
            const int hq = idx >> 10, f = (idx >> 6) & 15, l = idx & 63;
            const int lf = l & 15, lk = l >> 4;
            const size_t grow = (((size_t)(lf & 3)) << 9) + j0 + (hq << 2) + (lf >> 2);
            *(u16x8*)&sA[idx << 3] = *(const u16x8*)(w0l + (grow << 9) + (f << 5) + (lk << 3));
        }
        // A-hi into VGPRs: [hq*4+ck], k = kq*128 + ck*32 + kg*8
        bf16x8 Ah_[16];
#pragma unroll
        for (int hq = 0; hq < 4; ++hq) {
            const size_t grow = (((size_t)(fr & 3)) << 9) + j0 + (hq << 2) + (fr >> 2);
#pragma unroll
            for (int ck = 0; ck < 4; ++ck)
                Ah_[(hq << 2) | ck] = *(const bf16x8*)(
                    w0h + (grow << 9) + (kq << 7) + (ck << 5) + (kg << 3));
        }
        const int eh = tid >> 5;        // epilogue hidden-local 0..15
        const int hidden = j0 + eh;
        float c_reg = c0ws[((size_t)eb << 9) + hidden];
        __syncthreads();

        for (int jj = 0; jj < Tc; ++jj) {
            const int t = t0 + jj;
            float xv[4];
#pragma unroll
            for (int g = 0; g < 4; ++g)
                xv[g] = xg[(((size_t)eb * Tc + jj) << 11) + (g << 9) + hidden];
            SPIN_WAIT(jj, jj - 6);
            const u16* bHp = r0H + (((size_t)((t - 1) & 7)) << 14) + bko;
            const u16* bLp = r0L + (((size_t)((t - 1) & 7)) << 14) + bko;
            bf16x8 vb[4], vl[4];
#pragma unroll
            for (int ck = 0; ck < 4; ++ck) {
                LDG16(vb[ck], bHp + (ck << 5));
                LDG16(vl[ck], bLp + (ck << 5));
            }
            f32x4 s0[4] = {}, s1[4] = {}, s2[4] = {};
            bf16x8 Al_[16];
#pragma unroll
            for (int hq = 0; hq < 4; ++hq)
#pragma unroll
                for (int ck = 0; ck < 4; ++ck)
                    Al_[(hq << 2) | ck] = *(const bf16x8*)&sA[
                        ((((hq << 4) + (kq << 2) + ck) << 6) + lane) << 3];
            VMCNT0(); SBAR();
#pragma unroll
            for (int hq = 0; hq < 4; ++hq)
#pragma unroll
                for (int ck = 0; ck < 4; ++ck) {
                    s0[hq] = MFMA16(Ah_[(hq << 2) | ck], vb[ck], s0[hq]);
                    s1[hq] = MFMA16(Ah_[(hq << 2) | ck], vl[ck], s1[hq]);
                    s2[hq] = MFMA16(Al_[(hq << 2) | ck], vb[ck], s2[hq]);
                }
#pragma unroll
            for (int hq = 0; hq < 4; ++hq) {
                f32x4 sv = s0[hq] + s1[hq] + s2[hq];
                const int h16 = (hq << 2) + kg;
                *(f32x4*)&sred[((h16 << 5) + batch) * 20 + (kq << 2)] = sv;
            }
            __syncthreads();
            // epilogue: thread (eh, eb)
            {
                const int base = ((eh << 5) + eb) * 20;
                const f32x4 q0 = *(const f32x4*)&sred[base];
                const f32x4 q1 = *(const f32x4*)&sred[base + 4];
                const f32x4 q2 = *(const f32x4*)&sred[base + 8];
                const f32x4 q3 = *(const f32x4*)&sred[base + 12];
                const float gi = q0[0] + q1[0] + q2[0] + q3[0] + xv[0];
                const float gf = q0[1] + q1[1] + q2[1] + q3[1] + xv[1];
                const float gg = q0[2] + q1[2] + q2[2] + q3[2] + xv[2];
                const float go = q0[3] + q1[3] + q2[3] + q3[3] + xv[3];
                c_reg = sigf(gf) * c_reg + sigf(gi) * tanhf_(gg);
                const float h = sigf(go) * tanhf_(c_reg);
                const u16 hb = f2bf(h);
                const u16 lb = f2bf(h - bf2f(hb));
                spk[eh][eb] = (u32)hb | ((u32)lb << 16);
            }
            __syncthreads();
            if (tid < 128) {
                const int bt = tid & 31, h4 = (tid >> 5) << 2;
                const u32 p0 = spk[h4 + 0][bt], p1 = spk[h4 + 1][bt];
                const u32 p2 = spk[h4 + 2][bt], p3 = spk[h4 + 3][bt];
                const u64 hp = (u64)(p0 & 0xffffu) | ((u64)(p1 & 0xffffu) << 16)
                             | ((u64)(p2 & 0xffffu) << 32) | ((u64)(p3 & 0xffffu) << 48);
                const u64 lp = (u64)(p0 >> 16) | ((u64)(p1 >> 16) << 16)
                             | ((u64)(p2 >> 16) << 32) | ((u64)(p3 >> 16) << 48);
                const size_t wo = (((size_t)(t & 7)) << 14) + ((size_t)bt << 9) + j0 + h4;
                ST8(r0H + wo, hp);
                ST8(r0L + wo, lp);
            }
            VMCNT0();
            __syncthreads();
            if (tid == 0)
                __hip_atomic_store(flags + bid * FSTR, (u32)(jj + 1),
                                   __ATOMIC_RELAXED, __HIP_MEMORY_SCOPE_AGENT);
        }
        c0ws[((size_t)eb << 9) + hidden] = c_reg;
    } else {
        // ================= layer 1: 8 hidden =================
        const int j0 = (bid - NL0) << 3;
        // stage A-lo: idx -> (mat, hq, f, l); slot = mat*2+hq
#pragma unroll
        for (int i = 0; i < 8; ++i) {
            const int idx = tid + (i << 9);
            const int slot = idx >> 10, f = (idx >> 6) & 15, l = idx & 63;
            const int mat = slot >> 1, hq = slot & 1;
            const int lf = l & 15, lk = l >> 4;
            const size_t grow = (((size_t)(lf & 3)) << 9) + j0 + (hq << 2) + (lf >> 2);
            const u16* src = mat ? w1hh_l : w1ih_l;
            *(u16x8*)&sA[idx << 3] = *(const u16x8*)(src + (grow << 9) + (f << 5) + (lk << 3));
        }
        bf16x8 Ah_[16];
#pragma unroll
        for (int mat = 0; mat < 2; ++mat)
#pragma unroll
            for (int hq = 0; hq < 2; ++hq) {
                const size_t grow = (((size_t)(fr & 3)) << 9) + j0 + (hq << 2) + (fr >> 2);
                const u16* src = mat ? w1hh_h : w1ih_h;
#pragma unroll
                for (int ck = 0; ck < 4; ++ck)
                    Ah_[(((mat << 1) | hq) << 2) | ck] = *(const bf16x8*)(
                        src + (grow << 9) + (kq << 7) + (ck << 5) + (kg << 3));
            }
        const int eh = tid >> 5;       // 0..15, valid < 8
        const int hidden = j0 + (eh & 7);
        float bs[4], c_reg = 0.f;
        if (tid < 256) {
#pragma unroll
            for (int g = 0; g < 4; ++g) bs[g] = bsum1[(g << 9) + hidden];
            c_reg = c1ws[((size_t)eb << 9) + hidden];
        }
        __syncthreads();

        for (int jj = 0; jj < NS; ++jj) {
            const int t = t0 + jj - 1;
            SPIN_WAIT(jj, jj);
            if (t >= 0) {
                const u16* aHp = r0H + (((size_t)(t & 7)) << 14) + bko;
                const u16* aLp = r0L + (((size_t)(t & 7)) << 14) + bko;
                const u16* bHp = r1H + (((size_t)((t - 1) & 7)) << 14) + bko;
                const u16* bLp = r1L + (((size_t)((t - 1) & 7)) << 14) + bko;
                bf16x8 va[4], ua[4], vb[4], ub[4];
#pragma unroll
                for (int ck = 0; ck < 4; ++ck) {
                    LDG16(va[ck], aHp + (ck << 5));
                    LDG16(ua[ck], aLp + (ck << 5));
                    LDG16(vb[ck], bHp + (ck << 5));
                    LDG16(ub[ck], bLp + (ck << 5));
                }
                bf16x8 Al_[16];
#pragma unroll
                for (int s = 0; s < 4; ++s)
#pragma unroll
                    for (int ck = 0; ck < 4; ++ck)
                        Al_[(s << 2) | ck] = *(const bf16x8*)&sA[
                            ((((s << 4) + (kq << 2) + ck) << 6) + lane) << 3];
                f32x4 s0[2] = {}, s1[2] = {}, s2[2] = {};
                VMCNT0(); SBAR();
#pragma unroll
                for (int hq = 0; hq < 2; ++hq)
#pragma unroll
                    for (int ck = 0; ck < 4; ++ck) {
                        const int ia = (hq << 2) | ck;          // ih tiles
                        const int ib = ((2 + hq) << 2) | ck;    // hh tiles
                        s0[hq] = MFMA16(Ah_[ia], va[ck], s0[hq]);
                        s1[hq] = MFMA16(Ah_[ia], ua[ck], s1[hq]);
                        s2[hq] = MFMA16(Al_[ia], va[ck], s2[hq]);
                        s0[hq] = MFMA16(Ah_[ib], vb[ck], s0[hq]);
                        s1[hq] = MFMA16(Ah_[ib], ub[ck], s1[hq]);
                        s2[hq] = MFMA16(Al_[ib], vb[ck], s2[hq]);
                    }
#pragma unroll
                for (int hq = 0; hq < 2; ++hq) {
                    f32x4 sv = s0[hq] + s1[hq] + s2[hq];
                    const int h8 = (hq << 2) + kg;
                    *(f32x4*)&sred[((h8 << 5) + batch) * 20 + (kq << 2)] = sv;
                }
            }
            __syncthreads();
            if (t >= 0 && tid < 256) {
                const int base = ((eh << 5) + eb) * 20;
                const f32x4 q0 = *(const f32x4*)&sred[base];
                const f32x4 q1 = *(const f32x4*)&sred[base + 4];
                const f32x4 q2 = *(const f32x4*)&sred[base + 8];
                const f32x4 q3 = *(const f32x4*)&sred[base + 12];
                const float gi = q0[0] + q1[0] + q2[0] + q3[0] + bs[0];
                const float gf = q0[1] + q1[1] + q2[1] + q3[1] + bs[1];
                const float gg = q0[2] + q1[2] + q2[2] + q3[2] + bs[2];
                const float go = q0[3] + q1[3] + q2[3] + q3[3] + bs[3];
                c_reg = sigf(gf) * c_reg + sigf(gi) * tanhf_(gg);
                const float h = sigf(go) * tanhf_(c_reg);
                const u16 hb = f2bf(h);
                const u16 lb = f2bf(h - bf2f(hb));
                spk[eh][eb] = (u32)hb | ((u32)lb << 16);
            }
            __syncthreads();
            if (t >= 0 && tid < 64) {
                const int bt = tid & 31, h4 = (tid >> 5) << 2;
                const u32 p0 = spk[h4 + 0][bt], p1 = spk[h4 + 1][bt];
                const u32 p2 = spk[h4 + 2][bt], p3 = spk[h4 + 3][bt];
                const u64 hp = (u64)(p0 & 0xffffu) | ((u64)(p1 & 0xffffu) << 16)
                             | ((u64)(p2 & 0xffffu) << 32) | ((u64)(p3 & 0xffffu) << 48);
                const u64 lp = (u64)(p0 >> 16) | ((u64)(p1 >> 16) << 16)
                             | ((u64)(p2 >> 16) << 32) | ((u64)(p3 >> 16) << 48);
                const size_t wo = (((size_t)(t & 7)) << 14) + ((size_t)bt << 9) + j0 + h4;
                ST8(r1H + wo, hp);
                ST8(r1L + wo, lp);
                float4 o;
                o.x = bf2f((u16)(p0 & 0xffffu)) + bf2f((u16)(p0 >> 16));
                o.y = bf2f((u16)(p1 & 0xffffu)) + bf2f((u16)(p1 >> 16));
                o.z = bf2f((u16)(p2 & 0xffffu)) + bf2f((u16)(p2 >> 16));
                o.w = bf2f((u16)(p3 & 0xffffu)) + bf2f((u16)(p3 >> 16));
                *(float4*)(out1 + (((size_t)bt * T + t) << 9) + j0 + h4) = o;
            }
            VMCNT0();
            __syncthreads();
            if (tid == 0)
                __hip_atomic_store(flags + bid * FSTR, (u32)(jj + 1),
                                   __ATOMIC_RELAXED, __HIP_MEMORY_SCOPE_AGENT);
        }
        if (tid < 256) c1ws[((size_t)eb << 9) + hidden] = c_reg;
    }
}

extern "C" void kernel_launch(void* const* d_in, const int* in_sizes, int n_in,
                              void* d_out, int out_size, void* d_ws, size_t ws_size,
                              hipStream_t stream)
{
    const float* x[3]   = {(const float*)d_in[0], (const float*)d_in[1],  (const float*)d_in[2]};
    const float* Wih[3] = {(const float*)d_in[3], (const float*)d_in[9],  (const float*)d_in[15]};
    const float* Whh[3] = {(const float*)d_in[4], (const float*)d_in[10], (const float*)d_in[16]};
    const float* bih[3] = {(const float*)d_in[5], (const float*)d_in[11], (const float*)d_in[17]};
    const float* bhh[3] = {(const float*)d_in[6], (const float*)d_in[12], (const float*)d_in[18]};
    const float* h0[3]  = {(const float*)d_in[7], (const float*)d_in[13], (const float*)d_in[19]};
    const float* c0[3]  = {(const float*)d_in[8], (const float*)d_in[14], (const float*)d_in[20]};
    const float* upW[2] = {(const float*)d_in[21], (const float*)d_in[23]};
    const float* upb[2] = {(const float*)d_in[22], (const float*)d_in[24]};

    float* ws = (float*)d_ws;
    float* bufA  = ws;
    float* bufB  = bufA + (size_t)NB * 256 * HD;
    float* c0ws  = bufB + (size_t)NB * 256 * HD;
    float* c1ws  = c0ws + (size_t)NB * HD;
    float* bsum1 = c1ws + (size_t)NB * HD;
    float* xg    = bsum1 + GD;

    const size_t head_f = 2 * (size_t)NB * 256 * HD + 2 * (size_t)NB * HD + GD;
    // tail: 6 weights (GD*HD u16) + 4 rings (NSLOT x NB*HD u16) + flags
    const size_t tail_f = 3 * (size_t)GD * HD + 2 * NSLOT * (size_t)NB * HD + 96 * FSTR + 64;
    int Tc_cap = 256;
    while (Tc_cap > 32 && (head_f + (size_t)NB * Tc_cap * GD + tail_f) * 4 > ws_size)
        Tc_cap >>= 1;

    u16* w0h    = (u16*)(xg + (size_t)NB * Tc_cap * GD);
    u16* w0l    = w0h + (size_t)GD * HD;
    u16* w1ih_h = w0l + (size_t)GD * HD;
    u16* w1ih_l = w1ih_h + (size_t)GD * HD;
    u16* w1hh_h = w1ih_l + (size_t)GD * HD;
    u16* w1hh_l = w1hh_h + (size_t)GD * HD;
    u16* r0H    = w1hh_l + (size_t)GD * HD;   // NSLOT x 16384 u16
    u16* r0L    = r0H + NSLOT * (size_t)NB * HD;
    u16* r1H    = r0L + NSLOT * (size_t)NB * HD;
    u16* r1L    = r1H + NSLOT * (size_t)NB * HD;
    u32* flags  = (u32*)(r1L + NSLOT * (size_t)NB * HD);

    auto tier = [&](const float* in, float* out1, int T, int tr) {
        const float* Wih0L = Wih[tr];
        const float* Whh0L = Whh[tr];
        const float* Wih1L = Wih[tr] + (size_t)GD * HD;
        const float* Whh1L = Whh[tr] + (size_t)GD * HD;

        split_kernel<<<(GD * HD) / 256, 256, 0, stream>>>(Whh0L, w0h, w0l, GD * HD);
        split_kernel<<<(GD * HD) / 256, 256, 0, stream>>>(Wih1L, w1ih_h, w1ih_l, GD * HD);
        split_kernel<<<(GD * HD) / 256, 256, 0, stream>>>(Whh1L, w1hh_h, w1hh_l, GD * HD);
        addv_kernel<<<GD / 256, 256, 0, stream>>>(bih[tr] + GD, bhh[tr] + GD, bsum1, GD);
        // h0/h1 init -> ring slot 7 (t=0 reads slot (t-1)&7 == 7)
        split_kernel<<<(NB * HD) / 256, 256, 0, stream>>>(
            h0[tr], r0H + 7 * (size_t)NB * HD, r0L + 7 * (size_t)NB * HD, NB * HD);
        split_kernel<<<(NB * HD) / 256, 256, 0, stream>>>(
            h0[tr] + (size_t)NB * HD, r1H + 7 * (size_t)NB * HD, r1L + 7 * (size_t)NB * HD, NB * HD);
        hipMemcpyAsync(c0ws, c0[tr], (size_t)NB * HD * sizeof(float),
                       hipMemcpyDeviceToDevice, stream);
        hipMemcpyAsync(c1ws, c0[tr] + (size_t)NB * HD, (size_t)NB * HD * sizeof(float),
                       hipMemcpyDeviceToDevice, stream);

        const int Tc = T < Tc_cap ? T : Tc_cap;
        int tc_bits = 0; while ((1 << tc_bits) < Tc) ++tc_bits;
        for (int t0 = 0; t0 < T; t0 += Tc) {
            dim3 g((NB * Tc) / 64, GD / 64);
            mfma_gemm<0><<<g, 256, 0, stream>>>(in, T, t0, tc_bits, Wih0L, GD,
                                                bih[tr], bhh[tr], xg, 0, 0);
            hipMemsetAsync(flags, 0, 96 * FSTR * sizeof(u32), stream);
            const bool last = (t0 + Tc >= T);
            const int NS = Tc + (last ? 1 : 0);
            const float* xg_p = xg; int Tc_a = Tc;
            const u16 *a0 = w0h, *a1 = w0l, *a2 = w1ih_h, *a3 = w1ih_l, *a4 = w1hh_h, *a5 = w1hh_l;
            const float* bs_p = bsum1;
            u16 *p0H = r0H, *p0L = r0L, *p1H = r1H, *p1L = r1L;
            float *c0p = c0ws, *c1p = c1ws, *o1 = out1;
            int T_a = T, t0_a = t0, NS_a = NS;
            u32* fl = flags;
            void* args[] = {(void*)&xg_p, (void*)&Tc_a,
                            (void*)&a0, (void*)&a1, (void*)&a2, (void*)&a3, (void*)&a4, (void*)&a5,
                            (void*)&bs_p,
                            (void*)&p0H, (void*)&p0L, (void*)&p1H, (void*)&p1L,
                            (void*)&c0p, (void*)&c1p, (void*)&o1,
                            (void*)&T_a, (void*)&t0_a, (void*)&NS_a, (void*)&fl};
            hipLaunchCooperativeKernel((const void*)lstm_scan5, dim3(NL0 + NL1), dim3(512),
                                       args, 0, stream);
        }
    };

    float* dout = (float*)d_out;

    // Tier 0 (T=128): l1 series -> bufB
    tier(x[0], bufB, 128, 0);
    {   // upsample 0: bufB (B,128,512) -> bufA (B,256,512) + x1
        dim3 g((NB * 128) / 64, 1024 / 64);
        mfma_gemm<1><<<g, 256, 0, stream>>>(bufB, 0, 0, 0, upW[0], 1024,
                                            upb[0], x[1], bufA, 7, 1);
    }
    // Tier 1 (T=256): input bufA, l1 series -> bufB
    tier(bufA, bufB, 256, 1);
    {   // upsample 1: bufB (B,256,512) -> dout (B,2048,512) + x2
        dim3 g((NB * 256) / 64, 4096 / 64);
        mfma_gemm<1><<<g, 256, 0, stream>>>(bufB, 0, 0, 0, upW[1], 4096,
                                            upb[1], x[2], dout, 8, 3);
    }
    // Tier 2 (T=2048): input dout (chunk reads precede in-place l1 writes), l1 -> dout
    tier(dout, dout, 2048, 2);
}

// Round 9
// 11126.141 us; speedup vs baseline: 3.2035x; 1.4324x over previous
//
#include <hip/hip_runtime.h>
#include <cstddef>
#include <cstdint>

#define NB 32     // batch
#define HD 512    // hidden
#define GD 2048   // 4*hidden
#define NL0 32    // layer-0 blocks (16 hidden each)
#define NL1 64    // layer-1 blocks (8 hidden each)
#define FSTR 64   // u32 stride between flags (256 B each)
#define NSLOT 8   // ring slots
#define LOSC 0.00048828125f   // 1/2048

typedef unsigned short u16;
typedef unsigned int u32;
typedef unsigned long long u64;
typedef _Float16 f16;
typedef __attribute__((ext_vector_type(8))) _Float16 f16x8;
typedef __attribute__((ext_vector_type(4))) float f32x4;

#define MFMAF(a, b, c) __builtin_amdgcn_mfma_f32_16x16x32_f16((a), (b), (c), 0, 0, 0)
#define AT_LD(p)   __hip_atomic_load((p), __ATOMIC_RELAXED, __HIP_MEMORY_SCOPE_AGENT)

#define LDG16(dst, p) \
    asm volatile("global_load_dwordx4 %0, %1, off sc0 sc1" : "=&v"(dst) : "v"(p))
#define ST8(p, v) \
    asm volatile("global_store_dwordx2 %0, %1, off sc0 sc1" :: "v"(p), "v"(v) : "memory")
#define VMCNT0() asm volatile("s_waitcnt vmcnt(0)" ::: "memory")
#define SBAR()   __builtin_amdgcn_sched_barrier(0)

__device__ __forceinline__ float sigf(float x)   { return 1.0f / (1.0f + __expf(-x)); }
__device__ __forceinline__ float tanhf_(float x) { return 2.0f / (1.0f + __expf(-2.0f * x)) - 1.0f; }

__device__ __forceinline__ u16 f2h_bits(float x) {
    f16 h = (f16)x; union { f16 f; u16 u; } c; c.f = h; return c.u;
}
__device__ __forceinline__ float h2f(u16 b) {
    union { u16 u; f16 f; } c; c.u = b; return (float)c.f;
}

// convert 8 fp32 -> f16x8
__device__ __forceinline__ void cvt8(const float4 a, const float4 b, f16x8& o) {
    o[0] = (f16)a.x; o[1] = (f16)a.y; o[2] = (f16)a.z; o[3] = (f16)a.w;
    o[4] = (f16)b.x; o[5] = (f16)b.y; o[6] = (f16)b.z; o[7] = (f16)b.w;
}
// split 8 fp32 -> f16 hi + f16 lo*2048
__device__ __forceinline__ void split8f(const float4 a, const float4 b, f16x8& hi, f16x8& lo) {
    float v[8] = {a.x, a.y, a.z, a.w, b.x, b.y, b.z, b.w};
#pragma unroll
    for (int q = 0; q < 8; ++q) {
        const f16 h = (f16)v[q];
        hi[q] = h;
        lo[q] = (f16)((v[q] - (float)h) * 2048.0f);
    }
}

// weights: fp32 -> f16 hi + scaled f16 lo (bit-stored in u16 arrays)
__global__ __launch_bounds__(256) void wsplit_kernel(
    const float* __restrict__ src, u16* __restrict__ hi, u16* __restrict__ lo, int n)
{
    const int i = blockIdx.x * 256 + threadIdx.x;
    if (i < n) {
        const float x = src[i];
        const f16 h = (f16)x;
        union { f16 f; u16 u; } c; c.f = h;
        hi[i] = c.u;
        lo[i] = f2h_bits((x - (float)h) * 2048.0f);
    }
}

__global__ __launch_bounds__(256) void cvtf_kernel(
    const float* __restrict__ src, u16* __restrict__ dst, int n)
{
    const int i = blockIdx.x * 256 + threadIdx.x;
    if (i < n) dst[i] = f2h_bits(src[i]);
}

__global__ __launch_bounds__(256) void addv_kernel(
    const float* __restrict__ a, const float* __restrict__ b, float* __restrict__ o, int n)
{
    const int i = blockIdx.x * 256 + threadIdx.x;
    if (i < n) o[i] = a[i] + b[i];
}

// f16-split MFMA GEMM, C tile 64x64, K=512. A single-f16; W split hi + lo*2048.
template<int MODE>
__global__ __launch_bounds__(256) void mfma_gemm(
    const float* __restrict__ A, int T, int t0, int tc_bits,
    const float* __restrict__ W, int N,
    const float* __restrict__ b1, const float* __restrict__ b2x,
    float* __restrict__ out, int t_bits, int u_bits)
{
    __shared__ __align__(16) u16 As[64][40], Bh[64][40], Bl[64][40];
    const int tid = threadIdx.x;
    const int m0 = blockIdx.x << 6, n0 = blockIdx.y << 6;

    const int ar = tid >> 2, aks = (tid & 3) << 3;
    const float* aPtr;
    if (MODE == 0) {
        const int rg = m0 + ar;
        const int b = rg >> tc_bits;
        const int tt = t0 + (rg & ((1 << tc_bits) - 1));
        aPtr = A + (((size_t)b * T + tt) << 9) + aks;
    } else {
        aPtr = A + (((size_t)(m0 + ar)) << 9) + aks;
    }
    const float* bPtr = nullptr;
    int bkk = 0, bns = 0;
    if (MODE == 0) {
        bPtr = W + (((size_t)(n0 + ar)) << 9) + aks;
    } else {
        bkk = tid >> 3; bns = (tid & 7) << 3;
        bPtr = W + (size_t)bkk * N + n0 + bns;
    }

    const int lane = tid & 63, wv = tid >> 6;
    const int fr = lane & 15, ko = (lane >> 4) << 3;
    f32x4 acc[4] = {}, accl[4] = {};

    for (int k0 = 0; k0 < HD; k0 += 32) {
        {
            const float4 a1 = *(const float4*)(aPtr + k0);
            const float4 a2 = *(const float4*)(aPtr + k0 + 4);
            f16x8 av; cvt8(a1, a2, av);
            *(f16x8*)&As[ar][aks] = av;
        }
        if (MODE == 0) {
            const float4 w1 = *(const float4*)(bPtr + k0);
            const float4 w2 = *(const float4*)(bPtr + k0 + 4);
            f16x8 vh, vl; split8f(w1, w2, vh, vl);
            *(f16x8*)&Bh[ar][aks] = vh;
            *(f16x8*)&Bl[ar][aks] = vl;
        } else {
            const float4 w1 = *(const float4*)(bPtr + (size_t)k0 * N);
            const float4 w2 = *(const float4*)(bPtr + (size_t)k0 * N + 4);
            f16x8 vh, vl; split8f(w1, w2, vh, vl);
#pragma unroll
            for (int q = 0; q < 8; ++q) {
                union { f16 f; u16 u; } ch, cl; ch.f = vh[q]; cl.f = vl[q];
                Bh[bns + q][bkk] = ch.u;
                Bl[bns + q][bkk] = cl.u;
            }
        }
        __syncthreads();
        const f16x8 ahf = *(const f16x8*)&As[(wv << 4) + fr][ko];
#pragma unroll
        for (int nt = 0; nt < 4; ++nt) {
            const f16x8 bhf = *(const f16x8*)&Bh[(nt << 4) + fr][ko];
            const f16x8 blf = *(const f16x8*)&Bl[(nt << 4) + fr][ko];
            acc[nt]  = MFMAF(ahf, bhf, acc[nt]);
            accl[nt] = MFMAF(ahf, blf, accl[nt]);
        }
        __syncthreads();
    }

    const int mlb = (wv << 4) + ((lane >> 4) << 2);
#pragma unroll
    for (int r = 0; r < 4; ++r) {
        const int mg = m0 + mlb + r;
#pragma unroll
        for (int nt = 0; nt < 4; ++nt) {
            const int n = n0 + (nt << 4) + fr;
            const float v = acc[nt][r] + accl[nt][r] * LOSC;
            if (MODE == 0) {
                out[((size_t)mg << 11) + n] = v + b1[n] + b2x[n];
            } else {
                const int bb = mg >> t_bits, tt = mg & ((1 << t_bits) - 1);
                const int uu = n >> 9, hh = n & 511;
                const size_t di = (((size_t)((((bb << t_bits) + tt) << u_bits) + uu)) << 9) + hh;
                out[di] = v + b1[n] + b2x[di];
            }
        }
    }
}

// ---------------- persistent fused 2-layer scan v5 ----------------
// 96 blocks x 512 threads. [0,32): layer0 (16 hidden); [32,96): layer1 (8 hidden).
// h crosses blocks as SINGLE f16 rings (8-slot), sc0sc1 ops. Weights f16-split:
// hi in VGPRs, lo*2048 staged once in LDS. Waves split K (kq,bh); gate == C-reg.
// Per-block padded flags; out1 stores after flag release (off critical path).
//   l0@jj: flags0 >= jj, flags1 >= jj-6   |   l1@jj: flags0 >= jj, flags1 >= jj

#define SPIN_WAIT(TGT0, TGT1) do { \
    if (tid < NL0 + NL1) { \
        const int tgt_ = (tid < NL0) ? (TGT0) : (TGT1); \
        if (tgt_ > 0) { \
            const u32* fp_ = flags + tid * FSTR; \
            int g_ = 0; \
            while ((int)AT_LD(fp_) < tgt_ && ++g_ < (1 << 24)) {} \
        } \
    } \
    SBAR(); \
    __syncthreads(); \
} while (0)

__global__ __launch_bounds__(512, 2) void lstm_scan6(
    const float* __restrict__ xg, int Tc,
    const u16* __restrict__ w0h, const u16* __restrict__ w0l,
    const u16* __restrict__ w1ih_h, const u16* __restrict__ w1ih_l,
    const u16* __restrict__ w1hh_h, const u16* __restrict__ w1hh_l,
    const float* __restrict__ bsum1,
    u16* __restrict__ r0, u16* __restrict__ r1,
    float* __restrict__ c0ws, float* __restrict__ c1ws,
    float* __restrict__ out1, int T, int t0, int NS,
    u32* __restrict__ flags)
{
    __shared__ __align__(16) u16 sA[32768];            // W-lo*2048 frags, 64 KB
    __shared__ __align__(16) float sred[16 * 32 * 20]; // 40 KB
    __shared__ u16 spk[16][33];
    const int tid = threadIdx.x;
    const int bid = blockIdx.x;
    const int lane = tid & 63, wv = tid >> 6;
    const int kq = wv >> 1, bh = wv & 1;
    const int fr = lane & 15, kg = lane >> 4;
    const int batch = (bh << 4) + fr;
    const int eb = tid & 31;
    const u32 bko = ((u32)batch << 9) + (kq << 7) + (kg << 3);

    if (bid < NL0) {
        // ================= layer 0: 16 hidden =================
        const int j0 = bid << 4;
#pragma unroll
        for (int i = 0; i < 8; ++i) {
            const int idx = tid + (i << 9);
            const int hq = idx >> 10, f = (idx >> 6) & 15, l = idx & 63;
            const int lf = l & 15, lk = l >> 4;
            const size_t grow = (((size_t)(lf & 3)) << 9) + j0 + (hq << 2) + (lf >> 2);
            *(f16x8*)&sA[idx << 3] = *(const f16x8*)(w0l + (grow << 9) + (f << 5) + (lk << 3));
        }
        f16x8 Ah_[16];
#pragma unroll
        for (int hq = 0; hq < 4; ++hq) {
            const size_t grow = (((size_t)(fr & 3)) << 9) + j0 + (hq << 2) + (fr >> 2);
#pragma unroll
            for (int ck = 0; ck < 4; ++ck)
                Ah_[(hq << 2) | ck] = *(const f16x8*)(
                    w0h + (grow << 9) + (kq << 7) + (ck << 5) + (kg << 3));
        }
        const int eh = tid >> 5;
        const int hidden = j0 + eh;
        float c_reg = c0ws[((size_t)eb << 9) + hidden];
        __syncthreads();

        for (int jj = 0; jj < Tc; ++jj) {
            const int t = t0 + jj;
            float xv[4];
#pragma unroll
            for (int g = 0; g < 4; ++g)
                xv[g] = xg[(((size_t)eb * Tc + jj) << 11) + (g << 9) + hidden];
            SPIN_WAIT(jj, jj - 6);
            const u16* bp = r0 + (((size_t)((t - 1) & 7)) << 14) + bko;
            f16x8 vb[4];
#pragma unroll
            for (int ck = 0; ck < 4; ++ck)
                LDG16(vb[ck], bp + (ck << 5));
            f16x8 Al_[16];
#pragma unroll
            for (int hq = 0; hq < 4; ++hq)
#pragma unroll
                for (int ck = 0; ck < 4; ++ck)
                    Al_[(hq << 2) | ck] = *(const f16x8*)&sA[
                        ((((hq << 4) + (kq << 2) + ck) << 6) + lane) << 3];
            f32x4 s0[4] = {}, s1[4] = {};
            VMCNT0(); SBAR();
#pragma unroll
            for (int hq = 0; hq < 4; ++hq)
#pragma unroll
                for (int ck = 0; ck < 4; ++ck) {
                    s0[hq] = MFMAF(Ah_[(hq << 2) | ck], vb[ck], s0[hq]);
                    s1[hq] = MFMAF(Al_[(hq << 2) | ck], vb[ck], s1[hq]);
                }
#pragma unroll
            for (int hq = 0; hq < 4; ++hq) {
                const f32x4 sv = s0[hq] + s1[hq] * LOSC;
                const int h16 = (hq << 2) + kg;
                *(f32x4*)&sred[((h16 << 5) + batch) * 20 + (kq << 2)] = sv;
            }
            __syncthreads();
            {
                const int base = ((eh << 5) + eb) * 20;
                const f32x4 q0 = *(const f32x4*)&sred[base];
                const f32x4 q1 = *(const f32x4*)&sred[base + 4];
                const f32x4 q2 = *(const f32x4*)&sred[base + 8];
                const f32x4 q3 = *(const f32x4*)&sred[base + 12];
                const float gi = q0[0] + q1[0] + q2[0] + q3[0] + xv[0];
                const float gf = q0[1] + q1[1] + q2[1] + q3[1] + xv[1];
                const float gg = q0[2] + q1[2] + q2[2] + q3[2] + xv[2];
                const float go = q0[3] + q1[3] + q2[3] + q3[3] + xv[3];
                c_reg = sigf(gf) * c_reg + sigf(gi) * tanhf_(gg);
                const float h = sigf(go) * tanhf_(c_reg);
                spk[eh][eb] = f2h_bits(h);
            }
            __syncthreads();
            if (tid < 128) {
                const int bt = tid & 31, h4 = (tid >> 5) << 2;
                const u64 hp = (u64)spk[h4 + 0][bt] | ((u64)spk[h4 + 1][bt] << 16)
                             | ((u64)spk[h4 + 2][bt] << 32) | ((u64)spk[h4 + 3][bt] << 48);
                const size_t wo = (((size_t)(t & 7)) << 14) + ((size_t)bt << 9) + j0 + h4;
                ST8(r0 + wo, hp);
            }
            VMCNT0();
            __syncthreads();
            if (tid == 0)
                __hip_atomic_store(flags + bid * FSTR, (u32)(jj + 1),
                                   __ATOMIC_RELAXED, __HIP_MEMORY_SCOPE_AGENT);
        }
        c0ws[((size_t)eb << 9) + hidden] = c_reg;
    } else {
        // ================= layer 1: 8 hidden =================
        const int j0 = (bid - NL0) << 3;
#pragma unroll
        for (int i = 0; i < 8; ++i) {
            const int idx = tid + (i << 9);
            const int slot = idx >> 10, f = (idx >> 6) & 15, l = idx & 63;
            const int mat = slot >> 1, hq = slot & 1;
            const int lf = l & 15, lk = l >> 4;
            const size_t grow = (((size_t)(lf & 3)) << 9) + j0 + (hq << 2) + (lf >> 2);
            const u16* src = mat ? w1hh_l : w1ih_l;
            *(f16x8*)&sA[idx << 3] = *(const f16x8*)(src + (grow << 9) + (f << 5) + (lk << 3));
        }
        f16x8 Ah_[16];
#pragma unroll
        for (int mat = 0; mat < 2; ++mat)
#pragma unroll
            for (int hq = 0; hq < 2; ++hq) {
                const size_t grow = (((size_t)(fr & 3)) << 9) + j0 + (hq << 2) + (fr >> 2);
                const u16* src = mat ? w1hh_h : w1ih_h;
#pragma unroll
                for (int ck = 0; ck < 4; ++ck)
                    Ah_[(((mat << 1) | hq) << 2) | ck] = *(const f16x8*)(
                        src + (grow << 9) + (kq << 7) + (ck << 5) + (kg << 3));
            }
        const int eh = tid >> 5;
        const int hidden = j0 + (eh & 7);
        float bs[4], c_reg = 0.f;
        if (tid < 256) {
#pragma unroll
            for (int g = 0; g < 4; ++g) bs[g] = bsum1[(g << 9) + hidden];
            c_reg = c1ws[((size_t)eb << 9) + hidden];
        }
        __syncthreads();

        for (int jj = 0; jj < NS; ++jj) {
            const int t = t0 + jj - 1;
            SPIN_WAIT(jj, jj);
            if (t >= 0) {
                const u16* ap = r0 + (((size_t)(t & 7)) << 14) + bko;
                const u16* bp = r1 + (((size_t)((t - 1) & 7)) << 14) + bko;
                f16x8 va[4], vb[4];
#pragma unroll
                for (int ck = 0; ck < 4; ++ck) {
                    LDG16(va[ck], ap + (ck << 5));
                    LDG16(vb[ck], bp + (ck << 5));
                }
                f16x8 Al_[16];
#pragma unroll
                for (int s = 0; s < 4; ++s)
#pragma unroll
                    for (int ck = 0; ck < 4; ++ck)
                        Al_[(s << 2) | ck] = *(const f16x8*)&sA[
                            ((((s << 4) + (kq << 2) + ck) << 6) + lane) << 3];
                f32x4 s0[2] = {}, s1[2] = {};
                VMCNT0(); SBAR();
#pragma unroll
                for (int hq = 0; hq < 2; ++hq)
#pragma unroll
                    for (int ck = 0; ck < 4; ++ck) {
                        const int ia = (hq << 2) | ck;
                        const int ib = ((2 + hq) << 2) | ck;
                        s0[hq] = MFMAF(Ah_[ia], va[ck], s0[hq]);
                        s1[hq] = MFMAF(Al_[ia], va[ck], s1[hq]);
                        s0[hq] = MFMAF(Ah_[ib], vb[ck], s0[hq]);
                        s1[hq] = MFMAF(Al_[ib], vb[ck], s1[hq]);
                    }
#pragma unroll
                for (int hq = 0; hq < 2; ++hq) {
                    const f32x4 sv = s0[hq] + s1[hq] * LOSC;
                    const int h8 = (hq << 2) + kg;
                    *(f32x4*)&sred[((h8 << 5) + batch) * 20 + (kq << 2)] = sv;
                }
            }
            __syncthreads();
            if (t >= 0 && tid < 256) {
                const int base = ((eh << 5) + eb) * 20;
                const f32x4 q0 = *(const f32x4*)&sred[base];
                const f32x4 q1 = *(const f32x4*)&sred[base + 4];
                const f32x4 q2 = *(const f32x4*)&sred[base + 8];
                const f32x4 q3 = *(const f32x4*)&sred[base + 12];
                const float gi = q0[0] + q1[0] + q2[0] + q3[0] + bs[0];
                const float gf = q0[1] + q1[1] + q2[1] + q3[1] + bs[1];
                const float gg = q0[2] + q1[2] + q2[2] + q3[2] + bs[2];
                const float go = q0[3] + q1[3] + q2[3] + q3[3] + bs[3];
                c_reg = sigf(gf) * c_reg + sigf(gi) * tanhf_(gg);
                const float h = sigf(go) * tanhf_(c_reg);
                spk[eh][eb] = f2h_bits(h);
            }
            __syncthreads();
            if (t >= 0 && tid < 64) {
                const int bt = tid & 31, h4 = (tid >> 5) << 2;
                const u64 hp = (u64)spk[h4 + 0][bt] | ((u64)spk[h4 + 1][bt] << 16)
                             | ((u64)spk[h4 + 2][bt] << 32) | ((u64)spk[h4 + 3][bt] << 48);
                const size_t wo = (((size_t)(t & 7)) << 14) + ((size_t)bt << 9) + j0 + h4;
                ST8(r1 + wo, hp);
            }
            VMCNT0();
            __syncthreads();
            if (tid == 0)
                __hip_atomic_store(flags + bid * FSTR, (u32)(jj + 1),
                                   __ATOMIC_RELAXED, __HIP_MEMORY_SCOPE_AGENT);
            // out1 write AFTER flag — off the critical path (consumed only at
            // kernel boundaries). spk re-written only after next SPIN's barrier.
            if (t >= 0 && tid < 64) {
                const int bt = tid & 31, h4 = (tid >> 5) << 2;
                float4 o;
                o.x = h2f(spk[h4 + 0][bt]);
                o.y = h2f(spk[h4 + 1][bt]);
                o.z = h2f(spk[h4 + 2][bt]);
                o.w = h2f(spk[h4 + 3][bt]);
                *(float4*)(out1 + (((size_t)bt * T + t) << 9) + j0 + h4) = o;
            }
        }
        if (tid < 256) c1ws[((size_t)eb << 9) + hidden] = c_reg;
    }
}

extern "C" void kernel_launch(void* const* d_in, const int* in_sizes, int n_in,
                              void* d_out, int out_size, void* d_ws, size_t ws_size,
                              hipStream_t stream)
{
    const float* x[3]   = {(const float*)d_in[0], (const float*)d_in[1],  (const float*)d_in[2]};
    const float* Wih[3] = {(const float*)d_in[3], (const float*)d_in[9],  (const float*)d_in[15]};
    const float* Whh[3] = {(const float*)d_in[4], (const float*)d_in[10], (const float*)d_in[16]};
    const float* bih[3] = {(const float*)d_in[5], (const float*)d_in[11], (const float*)d_in[17]};
    const float* bhh[3] = {(const float*)d_in[6], (const float*)d_in[12], (const float*)d_in[18]};
    const float* h0[3]  = {(const float*)d_in[7], (const float*)d_in[13], (const float*)d_in[19]};
    const float* c0[3]  = {(const float*)d_in[8], (const float*)d_in[14], (const float*)d_in[20]};
    const float* upW[2] = {(const float*)d_in[21], (const float*)d_in[23]};
    const float* upb[2] = {(const float*)d_in[22], (const float*)d_in[24]};

    float* ws = (float*)d_ws;
    float* bufA  = ws;
    float* bufB  = bufA + (size_t)NB * 256 * HD;
    float* c0ws  = bufB + (size_t)NB * 256 * HD;
    float* c1ws  = c0ws + (size_t)NB * HD;
    float* bsum1 = c1ws + (size_t)NB * HD;
    float* xg    = bsum1 + GD;

    const size_t head_f = 2 * (size_t)NB * 256 * HD + 2 * (size_t)NB * HD + GD;
    // tail: 6 weight arrays (GD*HD u16) + 2 rings (NSLOT x NB*HD u16) + flags
    const size_t tail_f = 3 * (size_t)GD * HD + NSLOT * (size_t)NB * HD + 96 * FSTR + 64;
    int Tc_cap = 256;
    while (Tc_cap > 32 && (head_f + (size_t)NB * Tc_cap * GD + tail_f) * 4 > ws_size)
        Tc_cap >>= 1;

    u16* w0h    = (u16*)(xg + (size_t)NB * Tc_cap * GD);
    u16* w0l    = w0h + (size_t)GD * HD;
    u16* w1ih_h = w0l + (size_t)GD * HD;
    u16* w1ih_l = w1ih_h + (size_t)GD * HD;
    u16* w1hh_h = w1ih_l + (size_t)GD * HD;
    u16* w1hh_l = w1hh_h + (size_t)GD * HD;
    u16* r0     = w1hh_l + (size_t)GD * HD;   // NSLOT x 16384 u16 (f16 bits)
    u16* r1     = r0 + NSLOT * (size_t)NB * HD;
    u32* flags  = (u32*)(r1 + NSLOT * (size_t)NB * HD);

    auto tier = [&](const float* in, float* out1, int T, int tr) {
        const float* Wih0L = Wih[tr];
        const float* Whh0L = Whh[tr];
        const float* Wih1L = Wih[tr] + (size_t)GD * HD;
        const float* Whh1L = Whh[tr] + (size_t)GD * HD;

        wsplit_kernel<<<(GD * HD) / 256, 256, 0, stream>>>(Whh0L, w0h, w0l, GD * HD);
        wsplit_kernel<<<(GD * HD) / 256, 256, 0, stream>>>(Wih1L, w1ih_h, w1ih_l, GD * HD);
        wsplit_kernel<<<(GD * HD) / 256, 256, 0, stream>>>(Whh1L, w1hh_h, w1hh_l, GD * HD);
        addv_kernel<<<GD / 256, 256, 0, stream>>>(bih[tr] + GD, bhh[tr] + GD, bsum1, GD);
        // h0/h1 init -> ring slot 7 (t=0 reads slot (t-1)&7 == 7)
        cvtf_kernel<<<(NB * HD) / 256, 256, 0, stream>>>(
            h0[tr], r0 + 7 * (size_t)NB * HD, NB * HD);
        cvtf_kernel<<<(NB * HD) / 256, 256, 0, stream>>>(
            h0[tr] + (size_t)NB * HD, r1 + 7 * (size_t)NB * HD, NB * HD);
        hipMemcpyAsync(c0ws, c0[tr], (size_t)NB * HD * sizeof(float),
                       hipMemcpyDeviceToDevice, stream);
        hipMemcpyAsync(c1ws, c0[tr] + (size_t)NB * HD, (size_t)NB * HD * sizeof(float),
                       hipMemcpyDeviceToDevice, stream);

        const int Tc = T < Tc_cap ? T : Tc_cap;
        int tc_bits = 0; while ((1 << tc_bits) < Tc) ++tc_bits;
        for (int t0 = 0; t0 < T; t0 += Tc) {
            dim3 g((NB * Tc) / 64, GD / 64);
            mfma_gemm<0><<<g, 256, 0, stream>>>(in, T, t0, tc_bits, Wih0L, GD,
                                                bih[tr], bhh[tr], xg, 0, 0);
            hipMemsetAsync(flags, 0, 96 * FSTR * sizeof(u32), stream);
            const bool last = (t0 + Tc >= T);
            const int NS = Tc + (last ? 1 : 0);
            const float* xg_p = xg; int Tc_a = Tc;
            const u16 *a0 = w0h, *a1 = w0l, *a2 = w1ih_h, *a3 = w1ih_l, *a4 = w1hh_h, *a5 = w1hh_l;
            const float* bs_p = bsum1;
            u16 *p0 = r0, *p1 = r1;
            float *c0p = c0ws, *c1p = c1ws, *o1 = out1;
            int T_a = T, t0_a = t0, NS_a = NS;
            u32* fl = flags;
            void* args[] = {(void*)&xg_p, (void*)&Tc_a,
                            (void*)&a0, (void*)&a1, (void*)&a2, (void*)&a3, (void*)&a4, (void*)&a5,
                            (void*)&bs_p, (void*)&p0, (void*)&p1,
                            (void*)&c0p, (void*)&c1p, (void*)&o1,
                            (void*)&T_a, (void*)&t0_a, (void*)&NS_a, (void*)&fl};
            hipLaunchCooperativeKernel((const void*)lstm_scan6, dim3(NL0 + NL1), dim3(512),
                                       args, 0, stream);
        }
    };

    float* dout = (float*)d_out;

    // Tier 0 (T=128): l1 series -> bufB
    tier(x[0], bufB, 128, 0);
    {   // upsample 0: bufB (B,128,512) -> bufA (B,256,512) + x1
        dim3 g((NB * 128) / 64, 1024 / 64);
        mfma_gemm<1><<<g, 256, 0, stream>>>(bufB, 0, 0, 0, upW[0], 1024,
                                            upb[0], x[1], bufA, 7, 1);
    }
    // Tier 1 (T=256): input bufA, l1 series -> bufB
    tier(bufA, bufB, 256, 1);
    {   // upsample 1: bufB (B,256,512) -> dout (B,2048,512) + x2
        dim3 g((NB * 256) / 64, 4096 / 64);
        mfma_gemm<1><<<g, 256, 0, stream>>>(bufB, 0, 0, 0, upW[1], 4096,
                                            upb[1], x[2], dout, 8, 3);
    }
    // Tier 2 (T=2048): input dout (chunk reads precede in-place l1 writes), l1 -> dout
    tier(dout, dout, 2048, 2);
}